// Round 13
// baseline (2397.367 us; speedup 1.0000x reference)
//
#include <hip/hip_runtime.h>
#include <math.h>

#define NN 1024

typedef __attribute__((ext_vector_type(8))) short bf16x8;
typedef __attribute__((ext_vector_type(4))) short bf16x4;
typedef __attribute__((ext_vector_type(4))) float f32x4;
typedef __attribute__((ext_vector_type(2))) float f32x2;
typedef __attribute__((ext_vector_type(4))) unsigned int u32x4;

#if __has_builtin(__builtin_amdgcn_mfma_f32_16x16x16bf16_1k)
#define HAVE_MFMA16 1
#define MFMA16(a, b, c) __builtin_amdgcn_mfma_f32_16x16x16bf16_1k((a), (b), (c), 0, 0, 0)
#else
#define HAVE_MFMA16 0
#endif

__device__ __forceinline__ float sigmoidf_(float x) { return 1.0f / (1.0f + __expf(-x)); }

__device__ __forceinline__ unsigned int pk2(float a, float b) {
    return __builtin_amdgcn_perm(__float_as_uint(a) + 0x8000u,
                                 __float_as_uint(b) + 0x8000u, 0x03020706u);
}
__device__ __forceinline__ unsigned int pkcvt(float a, float b) {
#if __has_builtin(__builtin_amdgcn_cvt_pk_bf16_f32)
    return __builtin_bit_cast(unsigned int, __builtin_amdgcn_cvt_pk_bf16_f32(a, b));
#else
    return pk2(a, b);
#endif
}
__device__ __forceinline__ unsigned short f2bf_rne(float a) {
    unsigned int ua = __float_as_uint(a);
    ua += 0x7fffu + ((ua >> 16) & 1u);
    return (unsigned short)(ua >> 16);
}
__device__ __forceinline__ unsigned int pk2b(float a, float b) {
    return (unsigned int)f2bf_rne(a) | ((unsigned int)f2bf_rne(b) << 16);
}

// cfg layout (dwords): see r12.  flags: 5*1024 ints after mpart.
#define CFG_FLOATS 3584

// ---------------------------------------------------------------------------
// k_pre: blocks 0..1023 transpose J -> Jt; 1024..1151 init h,u0,v;
//        block 1152 cfg; block 1153 zeroes step flags.
// ---------------------------------------------------------------------------
__global__ __launch_bounds__(256) void k_pre(
    const float* __restrict__ J, const float* __restrict__ b,
    const float* __restrict__ W1, const float* __restrict__ b1,
    const float* __restrict__ W2, const float* __restrict__ b2,
    const float* __restrict__ W3, const float* __restrict__ b3,
    float* __restrict__ Jt, float* __restrict__ h,
    float* __restrict__ u0, float* __restrict__ v, float* __restrict__ cfg,
    int* __restrict__ flags)
{
    __shared__ float tile[32][33];
    const int t = blockIdx.x;
    const int tid = threadIdx.x;
    if (t < 1024) {
        int tx = (t & 31) * 32, ty = (t >> 5) * 32;
        int x = tid & 31, y = tid >> 5;
#pragma unroll
        for (int r = 0; r < 4; r++)
            tile[y + 8 * r][x] = J[(size_t)(ty + y + 8 * r) * NN + tx + x];
        __syncthreads();
#pragma unroll
        for (int r = 0; r < 4; r++)
            Jt[(size_t)(tx + y + 8 * r) * NN + ty + x] = tile[x][y + 8 * r];
    } else if (t < 1152) {
        int idx = (t - 1024) * 256 + tid;
        int row = idx >> 5, mm = idx & 31;
        float bi = b[row];
        h[idx]  = 0.f;
        u0[idx] = bi * W1[mm * 67 + 65];
        v[idx]  = fmaf(bi, W1[mm * 67 + 66], b1[mm]);
    } else if (t == 1153) {
        for (int i = tid; i < 5 * 1024; i += 256) flags[i] = 0;
    } else if (tid < 64) {
        const int l = tid, p = l & 15, q = l >> 4;
        union FU { unsigned int d[4]; unsigned short s[8]; } t0, t1, t2, t3;
        float wj[8];
#pragma unroll
        for (int jj = 0; jj < 8; jj++) {
            int k = q * 8 + jj;
            t0.s[jj] = f2bf_rne(W2[p * 32 + k]);
            t1.s[jj] = f2bf_rne(W2[(16 + p) * 32 + k]);
            t2.s[jj] = f2bf_rne(W3[p * 32 + k]);
            t3.s[jj] = f2bf_rne(W3[(16 + p) * 32 + k]);
            wj[jj] = W1[k * 67 + 64];
        }
        u32x4* cw = (u32x4*)cfg;
        cw[l]       = *(u32x4*)t0.d;
        cw[64 + l]  = *(u32x4*)t1.d;
        cw[128 + l] = *(u32x4*)t2.d;
        cw[192 + l] = *(u32x4*)t3.d;
        f32x4* cf = (f32x4*)(cfg + 1024);
        f32x4 v0, v1, v2, v3;
#pragma unroll
        for (int r = 0; r < 4; r++) {
            v0[r] = b2[q * 4 + r];  v1[r] = b2[16 + q * 4 + r];
            v2[r] = b3[q * 4 + r];  v3[r] = b3[16 + q * 4 + r];
        }
        cf[l] = v0; cf[64 + l] = v1; cf[128 + l] = v2; cf[192 + l] = v3;
        f32x4* cj = (f32x4*)(cfg + 2048);
        f32x4 wlo, whi;
#pragma unroll
        for (int r = 0; r < 4; r++) { wlo[r] = wj[r]; whi[r] = wj[4 + r]; }
        cj[l] = wlo; cj[64 + l] = whi;

        const int g = p;
        u32x4 fa, fb;
        fa[0] = pk2b(W3[g * 32 + 4 * q + 0],      W3[g * 32 + 4 * q + 1]);
        fa[1] = pk2b(W3[g * 32 + 4 * q + 2],      W3[g * 32 + 4 * q + 3]);
        fa[2] = pk2b(W3[g * 32 + 16 + 4 * q + 0], W3[g * 32 + 16 + 4 * q + 1]);
        fa[3] = pk2b(W3[g * 32 + 16 + 4 * q + 2], W3[g * 32 + 16 + 4 * q + 3]);
        fb[0] = pk2b(W3[(16 + g) * 32 + 4 * q + 0],      W3[(16 + g) * 32 + 4 * q + 1]);
        fb[1] = pk2b(W3[(16 + g) * 32 + 4 * q + 2],      W3[(16 + g) * 32 + 4 * q + 3]);
        fb[2] = pk2b(W3[(16 + g) * 32 + 16 + 4 * q + 0], W3[(16 + g) * 32 + 16 + 4 * q + 1]);
        fb[3] = pk2b(W3[(16 + g) * 32 + 16 + 4 * q + 2], W3[(16 + g) * 32 + 16 + 4 * q + 3]);
        u32x4* cw2 = (u32x4*)(cfg + 2560);
        cw2[l] = fa; cw2[64 + l] = fb;
        f32x4* cb3 = (f32x4*)(cfg + 3072);
        f32x4 r0, r1;
#pragma unroll
        for (int r = 0; r < 4; r++) { r0[r] = b3[g]; r1[r] = b3[16 + g]; }
        cb3[l] = r0; cb3[64 + l] = r1;
    }
}

// ---------------------------------------------------------------------------
// k_step: one recurrence step.  Grid 2048: block bx -> j = bx>>1,
// half = bx&1 (i-range half*512, 4 waves x 4 pairs).  8 blocks/CU ->
// 32 waves/CU (2x latency hiding).  Partial sums to mpart; the block that
// finishes second (device atomicAdd on flags[j]) runs the GRU tail.
// ---------------------------------------------------------------------------
__global__ __launch_bounds__(256, 8) void k_step(
    const float* __restrict__ Jt, const float* __restrict__ cfg,
    const float* __restrict__ Wih, const float* __restrict__ bih,
    const float* __restrict__ bhh, const float* __restrict__ b,
    const float* __restrict__ b1, const float* __restrict__ W1,
    const float* __restrict__ R1, const float* __restrict__ rb1,
    const float* __restrict__ R2, const float* __restrict__ rb2,
    const float* __restrict__ R3, const float* __restrict__ rb3,
    float* __restrict__ h, float* __restrict__ v,
    const float* __restrict__ ui, float* __restrict__ uo,
    float* __restrict__ mpart, int* __restrict__ flags,
    float* __restrict__ out, int do_out)
{
    __shared__ float red[4 * 32];
    __shared__ float hm[64], gbuf[96], hnb[32], tb[32];
    __shared__ int amSecond;

    const int tid = threadIdx.x;
    const int w = tid >> 6;
    const int l = tid & 63;
    const int p = l & 15;
    const int q = l >> 4;
    const int j = blockIdx.x >> 1;
    const int half = blockIdx.x & 1;

    // ---- coalesced per-lane context ----
    union FU { bf16x8 v; u32x4 u4; } w2a0, w2a1;
    const u32x4* cw = (const u32x4*)cfg;
    w2a0.u4 = cw[l]; w2a1.u4 = cw[64 + l];
    const f32x4* cf = (const f32x4*)(cfg + 1024);
    const f32x4 b2v0 = cf[l], b2v1 = cf[64 + l];
    const f32x4* cj = (const f32x4*)(cfg + 2048);
    const f32x4 wlo = cj[l], whi = cj[64 + l];
    f32x2 wj2[4] = { {wlo[0], wlo[1]}, {wlo[2], wlo[3]}, {whi[0], whi[1]}, {whi[2], whi[3]} };

#if HAVE_MFMA16
    union B4 { bf16x4 v; unsigned int d[2]; } B0a, B1a, B0b, B1b;
    {
        const u32x4* cw2 = (const u32x4*)(cfg + 2560);
        u32x4 fa = cw2[l], fb = cw2[64 + l];
        B0a.d[0] = fa[0]; B0a.d[1] = fa[1]; B1a.d[0] = fa[2]; B1a.d[1] = fa[3];
        B0b.d[0] = fb[0]; B0b.d[1] = fb[1]; B1b.d[0] = fb[2]; B1b.d[1] = fb[3];
    }
    const f32x4* cb3 = (const f32x4*)(cfg + 3072);
    const f32x4 b3lo = cb3[l], b3hi = cb3[64 + l];
#else
    union FU w3a0, w3a1;
    w3a0.u4 = cw[128 + l]; w3a1.u4 = cw[192 + l];
    const f32x4 b3v0 = cf[128 + l], b3v1 = cf[192 + l];
    const int s0 = (p | ((l & 16) << 1)) << 2;
    const int s1 = s0 + 64;
    const bool qlo = (l & 32) == 0;
#endif

    f32x2 vv2[4];
    {
        float4 va = *(const float4*)(v + j * 32 + q * 8);
        float4 vb = *(const float4*)(v + j * 32 + q * 8 + 4);
        vv2[0] = f32x2{va.x, va.y}; vv2[1] = f32x2{va.z, va.w};
        vv2[2] = f32x2{vb.x, vb.y}; vv2[3] = f32x2{vb.z, vb.w};
    }

    f32x4 acc0 = {0.f, 0.f, 0.f, 0.f}, acc1 = {0.f, 0.f, 0.f, 0.f};

    // ---- 4 pairs (8 tiles), depth-2 pair prefetch ----
    const int ibase = half * 512 + w * 128;
    const float* jp = Jt + (size_t)j * NN + ibase + p;
    const float* up = ui + (size_t)(ibase + p) * 32 + q * 8;

    float  jw0[2], jw1[2];
    float4 ua0[2], ub0[2], ua1[2], ub1[2];
#pragma unroll
    for (int s = 0; s < 2; s++) {
        jw0[s] = jp[s * 32];       jw1[s] = jp[s * 32 + 16];
        ua0[s] = *(const float4*)(up + (size_t)s * 1024);
        ub0[s] = *(const float4*)(up + (size_t)s * 1024 + 4);
        ua1[s] = *(const float4*)(up + (size_t)s * 1024 + 512);
        ub1[s] = *(const float4*)(up + (size_t)s * 1024 + 516);
    }

#pragma unroll
    for (int tt = 0; tt < 4; ++tt) {
        const int sl = tt & 1;
        const float  jwA_c = jw0[sl], jwB_c = jw1[sl];
        const float4 uaA_c = ua0[sl], ubA_c = ub0[sl];
        const float4 uaB_c = ua1[sl], ubB_c = ub1[sl];
        if (tt < 2) {
            const float* jn = jp + (tt + 2) * 32;
            const float* un = up + (size_t)(tt + 2) * 1024;
            jw0[sl] = jn[0];  jw1[sl] = jn[16];
            ua0[sl] = *(const float4*)(un);
            ub0[sl] = *(const float4*)(un + 4);
            ua1[sl] = *(const float4*)(un + 512);
            ub1[sl] = *(const float4*)(un + 516);
        }

#pragma unroll
        for (int hh2 = 0; hh2 < 2; ++hh2) {
            const float  jw = hh2 ? jwB_c : jwA_c;
            const float4 ua_c = hh2 ? uaB_c : uaA_c;
            const float4 ub_c = hh2 ? ubB_c : ubA_c;

            const f32x2 jw2 = {jw, jw};
            const f32x2 z2 = {0.f, 0.f};
            const f32x4 z4 = {0.f, 0.f, 0.f, 0.f};

            f32x2 x0 = {ua_c.x, ua_c.y}, x1 = {ua_c.z, ua_c.w};
            f32x2 x2 = {ub_c.x, ub_c.y}, x3 = {ub_c.z, ub_c.w};
            x0 = jw2 * wj2[0] + (x0 + vv2[0]);
            x1 = jw2 * wj2[1] + (x1 + vv2[1]);
            x2 = jw2 * wj2[2] + (x2 + vv2[2]);
            x3 = jw2 * wj2[3] + (x3 + vv2[3]);
            x0 = __builtin_elementwise_max(x0, z2);
            x1 = __builtin_elementwise_max(x1, z2);
            x2 = __builtin_elementwise_max(x2, z2);
            x3 = __builtin_elementwise_max(x3, z2);

            union BU { u32x4 u4; bf16x8 v; unsigned int d[4]; } bx;
            bx.d[0] = pkcvt(x0[0], x0[1]);
            bx.d[1] = pkcvt(x1[0], x1[1]);
            bx.d[2] = pkcvt(x2[0], x2[1]);
            bx.d[3] = pkcvt(x3[0], x3[1]);

            f32x4 c0 = __builtin_amdgcn_mfma_f32_16x16x32_bf16(w2a0.v, bx.v, b2v0, 0, 0, 0);
            f32x4 c1 = __builtin_amdgcn_mfma_f32_16x16x32_bf16(w2a1.v, bx.v, b2v1, 0, 0, 0);
            c0 = __builtin_elementwise_max(c0, z4);
            c1 = __builtin_elementwise_max(c1, z4);

#if HAVE_MFMA16
            union B4 { bf16x4 v; unsigned int d[2]; } A0, A1;
            A0.d[0] = pkcvt(c0[0], c0[1]); A0.d[1] = pkcvt(c0[2], c0[3]);
            A1.d[0] = pkcvt(c1[0], c1[1]); A1.d[1] = pkcvt(c1[2], c1[3]);

            f32x4 e0 = MFMA16(A0.v, B0a.v, b3lo);
            e0 = MFMA16(A1.v, B1a.v, e0);
            f32x4 e1 = MFMA16(A0.v, B0b.v, b3hi);
            e1 = MFMA16(A1.v, B1b.v, e1);
            acc0 = acc0 + __builtin_elementwise_max(e0, z4);
            acc1 = acc1 + __builtin_elementwise_max(e1, z4);
#else
            const int d0 = (int)pkcvt(c0[0], c0[1]);
            const int d1 = (int)pkcvt(c0[2], c0[3]);
            const int d2 = (int)pkcvt(c1[0], c1[1]);
            const int d3 = (int)pkcvt(c1[2], c1[3]);
            const int A0_ = __builtin_amdgcn_ds_bpermute(s0, d0);
            const int A1_ = __builtin_amdgcn_ds_bpermute(s0, d1);
            const int A2_ = __builtin_amdgcn_ds_bpermute(s1, d0);
            const int A3_ = __builtin_amdgcn_ds_bpermute(s1, d1);
            const int B0_ = __builtin_amdgcn_ds_bpermute(s0, d2);
            const int B1_ = __builtin_amdgcn_ds_bpermute(s0, d3);
            const int B2_ = __builtin_amdgcn_ds_bpermute(s1, d2);
            const int B3_ = __builtin_amdgcn_ds_bpermute(s1, d3);
            union BU yr;
            yr.d[0] = (unsigned)(qlo ? A0_ : B0_);
            yr.d[1] = (unsigned)(qlo ? A1_ : B1_);
            yr.d[2] = (unsigned)(qlo ? A2_ : B2_);
            yr.d[3] = (unsigned)(qlo ? A3_ : B3_);
            f32x4 e0 = __builtin_amdgcn_mfma_f32_16x16x32_bf16(w3a0.v, yr.v, b3v0, 0, 0, 0);
            f32x4 e1 = __builtin_amdgcn_mfma_f32_16x16x32_bf16(w3a1.v, yr.v, b3v1, 0, 0, 0);
            acc0 = acc0 + __builtin_elementwise_max(e0, z4);
            acc1 = acc1 + __builtin_elementwise_max(e1, z4);
#endif
        }
    }

#if HAVE_MFMA16
    float s0v = acc0[0] + acc0[1] + acc0[2] + acc0[3];
    float s1v = acc1[0] + acc1[1] + acc1[2] + acc1[3];
    s0v += __shfl_xor(s0v, 16);  s0v += __shfl_xor(s0v, 32);
    s1v += __shfl_xor(s1v, 16);  s1v += __shfl_xor(s1v, 32);
    if (l < 16) { red[w * 32 + l] = s0v;  red[w * 32 + 16 + l] = s1v; }
#else
#pragma unroll
    for (int bit = 1; bit < 16; bit <<= 1) {
#pragma unroll
        for (int r = 0; r < 4; r++) {
            acc0[r] += __shfl_xor(acc0[r], bit);
            acc1[r] += __shfl_xor(acc1[r], bit);
        }
    }
    if (p == 0) {
#pragma unroll
        for (int r = 0; r < 4; r++) {
            red[w * 32 + q * 4 + r]      = acc0[r];
            red[w * 32 + 16 + q * 4 + r] = acc1[r];
        }
    }
#endif
    __syncthreads();

    // ---- publish partial, decide tail owner ----
    if (tid < 32)
        mpart[(half << 15) + j * 32 + tid] =
            red[tid] + red[32 + tid] + red[64 + tid] + red[96 + tid];
    __threadfence();                       // release mpart
    if (tid == 0) amSecond = atomicAdd(&flags[j], 1);
    __syncthreads();
    if (amSecond != 1) return;             // first finisher exits
    __threadfence();                       // acquire other half's mpart

    // ---- tail: GRU + u/v refresh (+ readout) ----
    if (tid < 64) {
        float val;
        if (tid < 32) val = h[j * 32 + tid];
        else {
            int s = tid - 32;
            val = mpart[j * 32 + s] + mpart[(1 << 15) + j * 32 + s];
        }
        hm[tid] = val;
    }
    __syncthreads();

    if (tid < 192) {
        const int row = tid >> 1, hh = tid & 1;
        const float* wr = Wih + row * 64 + hh * 32;
        const float* hhp = hm + hh * 32;
        float acc = 0.f;
#pragma unroll
        for (int k4 = 0; k4 < 8; k4++) {
            float4 w4 = *(const float4*)(wr + 4 * k4);
            acc = fmaf(w4.x, hhp[4 * k4 + 0], acc);
            acc = fmaf(w4.y, hhp[4 * k4 + 1], acc);
            acc = fmaf(w4.z, hhp[4 * k4 + 2], acc);
            acc = fmaf(w4.w, hhp[4 * k4 + 3], acc);
        }
        acc += __shfl_xor(acc, 1);
        if (hh == 0) gbuf[row] = acc + bih[row];
    }
    __syncthreads();

    if (tid < 32) {
        const int s = tid;
        float r = sigmoidf_(gbuf[s] + bhh[s]);
        float z = sigmoidf_(gbuf[32 + s] + bhh[32 + s]);
        float n = tanhf(gbuf[64 + s] + r * bhh[64 + s]);
        float hn_ = (1.0f - z) * n;
        hnb[s] = hn_;
        h[j * 32 + s] = hn_;
    }
    __syncthreads();

    if (tid < 64) {
        const int s = tid & 31;
        const bool isV = tid >= 32;
        const float bj = b[j];
        const float* wr = W1 + s * 67 + (isV ? 32 : 0);
        float acc = isV ? fmaf(bj, W1[s * 67 + 66], b1[s]) : bj * W1[s * 67 + 65];
#pragma unroll
        for (int k = 0; k < 32; k++) acc = fmaf(wr[k], hnb[k], acc);
        if (isV) v[j * 32 + s] = acc;
        else     uo[j * 32 + s] = acc;
    }

    if (do_out) {
        __syncthreads();
        if (tid < 32) {
            float a = rb1[tid];
            const float* rr = R1 + tid * 32;
#pragma unroll 8
            for (int k = 0; k < 32; k++) a = fmaf(rr[k], hnb[k], a);
            gbuf[tid] = fmaxf(a, 0.f);
        }
        __syncthreads();
        if (tid < 32) {
            float a = rb2[tid];
            const float* rr = R2 + tid * 32;
#pragma unroll 8
            for (int k = 0; k < 32; k++) a = fmaf(rr[k], gbuf[k], a);
            tb[tid] = fmaxf(a, 0.f);
        }
        __syncthreads();
        if (tid < 2) {
            float a = rb3[tid];
            const float* rr = R3 + tid * 32;
#pragma unroll 8
            for (int k = 0; k < 32; k++) a = fmaf(rr[k], tb[k], a);
            out[j * 2 + tid] = sigmoidf_(fmaxf(a, 0.f));
        }
    }
}

// ---------------------------------------------------------------------------
extern "C" void kernel_launch(void* const* d_in, const int* in_sizes, int n_in,
                              void* d_out, int out_size, void* d_ws, size_t ws_size,
                              hipStream_t stream)
{
    const float* J   = (const float*)d_in[0];
    const float* b   = (const float*)d_in[1];
    const float* W1  = (const float*)d_in[2];
    const float* b1  = (const float*)d_in[3];
    const float* W2  = (const float*)d_in[4];
    const float* b2  = (const float*)d_in[5];
    const float* W3  = (const float*)d_in[6];
    const float* b3  = (const float*)d_in[7];
    const float* Wih = (const float*)d_in[8];
    const float* bih = (const float*)d_in[9];
    const float* bhh = (const float*)d_in[10];
    const float* R1  = (const float*)d_in[11];
    const float* rb1 = (const float*)d_in[12];
    const float* R2  = (const float*)d_in[13];
    const float* rb2 = (const float*)d_in[14];
    const float* R3  = (const float*)d_in[15];
    const float* rb3 = (const float*)d_in[16];

    float* out = (float*)d_out;
    float* ws  = (float*)d_ws;
    float* h     = ws;
    float* v     = ws + 32768;
    float* u0    = ws + 65536;
    float* u1    = ws + 98304;
    float* Jt    = ws + 131072;
    float* cfg   = ws + 131072 + NN * NN;
    float* mpart = cfg + CFG_FLOATS;          // 2 * 32768 floats
    int*   flags = (int*)(mpart + 65536);     // 5 * 1024 ints

    k_pre<<<1154, 256, 0, stream>>>(J, b, W1, b1, W2, b2, W3, b3,
                                    Jt, h, u0, v, cfg, flags);
    for (int s = 0; s < 5; s++) {
        const float* ui = (s & 1) ? u1 : u0;
        float*       uo = (s & 1) ? u0 : u1;
        k_step<<<2048, 256, 0, stream>>>(Jt, cfg, Wih, bih, bhh, b, b1, W1,
                                         R1, rb1, R2, rb2, R3, rb3,
                                         h, v, ui, uo, mpart, flags + s * 1024,
                                         out, (s == 4) ? 1 : 0);
    }
}

// Round 14
// 1301.049 us; speedup vs baseline: 1.8426x; 1.8426x over previous
//
#include <hip/hip_runtime.h>
#include <math.h>

#define NN 1024

typedef __attribute__((ext_vector_type(8))) short bf16x8;
typedef __attribute__((ext_vector_type(4))) short bf16x4;
typedef __attribute__((ext_vector_type(4))) float f32x4;
typedef __attribute__((ext_vector_type(2))) float f32x2;
typedef __attribute__((ext_vector_type(4))) unsigned int u32x4;

#if __has_builtin(__builtin_amdgcn_mfma_f32_16x16x16bf16_1k)
#define HAVE_MFMA16 1
#define MFMA16(a, b, c) __builtin_amdgcn_mfma_f32_16x16x16bf16_1k((a), (b), (c), 0, 0, 0)
#else
#define HAVE_MFMA16 0
#endif

__device__ __forceinline__ float sigmoidf_(float x) { return 1.0f / (1.0f + __expf(-x)); }

__device__ __forceinline__ unsigned int pk2(float a, float b) {
    return __builtin_amdgcn_perm(__float_as_uint(a) + 0x8000u,
                                 __float_as_uint(b) + 0x8000u, 0x03020706u);
}
__device__ __forceinline__ unsigned int pkcvt(float a, float b) {
#if __has_builtin(__builtin_amdgcn_cvt_pk_bf16_f32)
    return __builtin_bit_cast(unsigned int, __builtin_amdgcn_cvt_pk_bf16_f32(a, b));
#else
    return pk2(a, b);
#endif
}
__device__ __forceinline__ unsigned short f2bf_rne(float a) {
    unsigned int ua = __float_as_uint(a);
    ua += 0x7fffu + ((ua >> 16) & 1u);
    return (unsigned short)(ua >> 16);
}
__device__ __forceinline__ unsigned int pk2b(float a, float b) {
    return (unsigned int)f2bf_rne(a) | ((unsigned int)f2bf_rne(b) << 16);
}

#define CFG_FLOATS 3584

// ---------------------------------------------------------------------------
// k_pre: blocks 0..1023 transpose J -> Jt; 1024..1151 init h,u0,v;
//        block 1152 cfg; block 1153 zeroes step flags.
// ---------------------------------------------------------------------------
__global__ __launch_bounds__(256) void k_pre(
    const float* __restrict__ J, const float* __restrict__ b,
    const float* __restrict__ W1, const float* __restrict__ b1,
    const float* __restrict__ W2, const float* __restrict__ b2,
    const float* __restrict__ W3, const float* __restrict__ b3,
    float* __restrict__ Jt, float* __restrict__ h,
    float* __restrict__ u0, float* __restrict__ v, float* __restrict__ cfg,
    int* __restrict__ flags)
{
    __shared__ float tile[32][33];
    const int t = blockIdx.x;
    const int tid = threadIdx.x;
    if (t < 1024) {
        int tx = (t & 31) * 32, ty = (t >> 5) * 32;
        int x = tid & 31, y = tid >> 5;
#pragma unroll
        for (int r = 0; r < 4; r++)
            tile[y + 8 * r][x] = J[(size_t)(ty + y + 8 * r) * NN + tx + x];
        __syncthreads();
#pragma unroll
        for (int r = 0; r < 4; r++)
            Jt[(size_t)(tx + y + 8 * r) * NN + ty + x] = tile[x][y + 8 * r];
    } else if (t < 1152) {
        int idx = (t - 1024) * 256 + tid;
        int row = idx >> 5, mm = idx & 31;
        float bi = b[row];
        h[idx]  = 0.f;
        u0[idx] = bi * W1[mm * 67 + 65];
        v[idx]  = fmaf(bi, W1[mm * 67 + 66], b1[mm]);
    } else if (t == 1153) {
        for (int i = tid; i < 5 * 1024; i += 256) flags[i] = 0;
    } else if (tid < 64) {
        const int l = tid, p = l & 15, q = l >> 4;
        union FU { unsigned int d[4]; unsigned short s[8]; } t0, t1, t2, t3;
        float wj[8];
#pragma unroll
        for (int jj = 0; jj < 8; jj++) {
            int k = q * 8 + jj;
            t0.s[jj] = f2bf_rne(W2[p * 32 + k]);
            t1.s[jj] = f2bf_rne(W2[(16 + p) * 32 + k]);
            t2.s[jj] = f2bf_rne(W3[p * 32 + k]);
            t3.s[jj] = f2bf_rne(W3[(16 + p) * 32 + k]);
            wj[jj] = W1[k * 67 + 64];
        }
        u32x4* cw = (u32x4*)cfg;
        cw[l]       = *(u32x4*)t0.d;
        cw[64 + l]  = *(u32x4*)t1.d;
        cw[128 + l] = *(u32x4*)t2.d;
        cw[192 + l] = *(u32x4*)t3.d;
        f32x4* cf = (f32x4*)(cfg + 1024);
        f32x4 v0, v1, v2, v3;
#pragma unroll
        for (int r = 0; r < 4; r++) {
            v0[r] = b2[q * 4 + r];  v1[r] = b2[16 + q * 4 + r];
            v2[r] = b3[q * 4 + r];  v3[r] = b3[16 + q * 4 + r];
        }
        cf[l] = v0; cf[64 + l] = v1; cf[128 + l] = v2; cf[192 + l] = v3;
        f32x4* cj = (f32x4*)(cfg + 2048);
        f32x4 wlo, whi;
#pragma unroll
        for (int r = 0; r < 4; r++) { wlo[r] = wj[r]; whi[r] = wj[4 + r]; }
        cj[l] = wlo; cj[64 + l] = whi;

        const int g = p;
        u32x4 fa, fb;
        fa[0] = pk2b(W3[g * 32 + 4 * q + 0],      W3[g * 32 + 4 * q + 1]);
        fa[1] = pk2b(W3[g * 32 + 4 * q + 2],      W3[g * 32 + 4 * q + 3]);
        fa[2] = pk2b(W3[g * 32 + 16 + 4 * q + 0], W3[g * 32 + 16 + 4 * q + 1]);
        fa[3] = pk2b(W3[g * 32 + 16 + 4 * q + 2], W3[g * 32 + 16 + 4 * q + 3]);
        fb[0] = pk2b(W3[(16 + g) * 32 + 4 * q + 0],      W3[(16 + g) * 32 + 4 * q + 1]);
        fb[1] = pk2b(W3[(16 + g) * 32 + 4 * q + 2],      W3[(16 + g) * 32 + 4 * q + 3]);
        fb[2] = pk2b(W3[(16 + g) * 32 + 16 + 4 * q + 0], W3[(16 + g) * 32 + 16 + 4 * q + 1]);
        fb[3] = pk2b(W3[(16 + g) * 32 + 16 + 4 * q + 2], W3[(16 + g) * 32 + 16 + 4 * q + 3]);
        u32x4* cw2 = (u32x4*)(cfg + 2560);
        cw2[l] = fa; cw2[64 + l] = fb;
        f32x4* cb3 = (f32x4*)(cfg + 3072);
        f32x4 r0, r1;
#pragma unroll
        for (int r = 0; r < 4; r++) { r0[r] = b3[g]; r1[r] = b3[16 + g]; }
        cb3[l] = r0; cb3[64 + l] = r1;
    }
}

// ---------------------------------------------------------------------------
// k_step: grid 2048 (2 blocks per j, 512 i's each, 4 waves x 4 pairs).
// __launch_bounds__(256,4): VGPR cap 128; actual ~64 -> 8 blocks/CU
// co-resident (VGPR-limited), 32 waves/CU.  NO forced 8-waves bound --
// r13's (256,8) caused catastrophic scratch spills (VGPR 32, 255 MB writes).
// Tail runs in the block that finishes second (device atomicAdd on flags[j]).
// ---------------------------------------------------------------------------
__global__ __launch_bounds__(256, 4) void k_step(
    const float* __restrict__ Jt, const float* __restrict__ cfg,
    const float* __restrict__ Wih, const float* __restrict__ bih,
    const float* __restrict__ bhh, const float* __restrict__ b,
    const float* __restrict__ b1, const float* __restrict__ W1,
    const float* __restrict__ R1, const float* __restrict__ rb1,
    const float* __restrict__ R2, const float* __restrict__ rb2,
    const float* __restrict__ R3, const float* __restrict__ rb3,
    float* __restrict__ h, float* __restrict__ v,
    const float* __restrict__ ui, float* __restrict__ uo,
    float* __restrict__ mpart, int* __restrict__ flags,
    float* __restrict__ out, int do_out)
{
    __shared__ float red[4 * 32];
    __shared__ float hm[64], gbuf[96], hnb[32], tb[32];
    __shared__ int amSecond;

    const int tid = threadIdx.x;
    const int w = tid >> 6;
    const int l = tid & 63;
    const int p = l & 15;
    const int q = l >> 4;
    const int j = blockIdx.x >> 1;
    const int half = blockIdx.x & 1;

    union FU { bf16x8 v; u32x4 u4; } w2a0, w2a1;
    const u32x4* cw = (const u32x4*)cfg;
    w2a0.u4 = cw[l]; w2a1.u4 = cw[64 + l];
    const f32x4* cf = (const f32x4*)(cfg + 1024);
    const f32x4 b2v0 = cf[l], b2v1 = cf[64 + l];
    const f32x4* cj = (const f32x4*)(cfg + 2048);
    const f32x4 wlo = cj[l], whi = cj[64 + l];
    f32x2 wj2[4] = { {wlo[0], wlo[1]}, {wlo[2], wlo[3]}, {whi[0], whi[1]}, {whi[2], whi[3]} };

#if HAVE_MFMA16
    union B4 { bf16x4 v; unsigned int d[2]; } B0a, B1a, B0b, B1b;
    {
        const u32x4* cw2 = (const u32x4*)(cfg + 2560);
        u32x4 fa = cw2[l], fb = cw2[64 + l];
        B0a.d[0] = fa[0]; B0a.d[1] = fa[1]; B1a.d[0] = fa[2]; B1a.d[1] = fa[3];
        B0b.d[0] = fb[0]; B0b.d[1] = fb[1]; B1b.d[0] = fb[2]; B1b.d[1] = fb[3];
    }
    const f32x4* cb3 = (const f32x4*)(cfg + 3072);
    const f32x4 b3lo = cb3[l], b3hi = cb3[64 + l];
#else
    union FU w3a0, w3a1;
    w3a0.u4 = cw[128 + l]; w3a1.u4 = cw[192 + l];
    const f32x4 b3v0 = cf[128 + l], b3v1 = cf[192 + l];
    const int s0 = (p | ((l & 16) << 1)) << 2;
    const int s1 = s0 + 64;
    const bool qlo = (l & 32) == 0;
#endif

    f32x2 vv2[4];
    {
        float4 va = *(const float4*)(v + j * 32 + q * 8);
        float4 vb = *(const float4*)(v + j * 32 + q * 8 + 4);
        vv2[0] = f32x2{va.x, va.y}; vv2[1] = f32x2{va.z, va.w};
        vv2[2] = f32x2{vb.x, vb.y}; vv2[3] = f32x2{vb.z, vb.w};
    }

    f32x4 acc0 = {0.f, 0.f, 0.f, 0.f}, acc1 = {0.f, 0.f, 0.f, 0.f};

    const int ibase = half * 512 + w * 128;
    const float* jp = Jt + (size_t)j * NN + ibase + p;
    const float* up = ui + (size_t)(ibase + p) * 32 + q * 8;

    float  jw0[2], jw1[2];
    float4 ua0[2], ub0[2], ua1[2], ub1[2];
#pragma unroll
    for (int s = 0; s < 2; s++) {
        jw0[s] = jp[s * 32];       jw1[s] = jp[s * 32 + 16];
        ua0[s] = *(const float4*)(up + (size_t)s * 1024);
        ub0[s] = *(const float4*)(up + (size_t)s * 1024 + 4);
        ua1[s] = *(const float4*)(up + (size_t)s * 1024 + 512);
        ub1[s] = *(const float4*)(up + (size_t)s * 1024 + 516);
    }

#pragma unroll
    for (int tt = 0; tt < 4; ++tt) {
        const int sl = tt & 1;
        const float  jwA_c = jw0[sl], jwB_c = jw1[sl];
        const float4 uaA_c = ua0[sl], ubA_c = ub0[sl];
        const float4 uaB_c = ua1[sl], ubB_c = ub1[sl];
        if (tt < 2) {
            const float* jn = jp + (tt + 2) * 32;
            const float* un = up + (size_t)(tt + 2) * 1024;
            jw0[sl] = jn[0];  jw1[sl] = jn[16];
            ua0[sl] = *(const float4*)(un);
            ub0[sl] = *(const float4*)(un + 4);
            ua1[sl] = *(const float4*)(un + 512);
            ub1[sl] = *(const float4*)(un + 516);
        }

#pragma unroll
        for (int hh2 = 0; hh2 < 2; ++hh2) {
            const float  jw = hh2 ? jwB_c : jwA_c;
            const float4 ua_c = hh2 ? uaB_c : uaA_c;
            const float4 ub_c = hh2 ? ubB_c : ubA_c;

            const f32x2 jw2 = {jw, jw};
            const f32x2 z2 = {0.f, 0.f};
            const f32x4 z4 = {0.f, 0.f, 0.f, 0.f};

            f32x2 x0 = {ua_c.x, ua_c.y}, x1 = {ua_c.z, ua_c.w};
            f32x2 x2 = {ub_c.x, ub_c.y}, x3 = {ub_c.z, ub_c.w};
            x0 = jw2 * wj2[0] + (x0 + vv2[0]);
            x1 = jw2 * wj2[1] + (x1 + vv2[1]);
            x2 = jw2 * wj2[2] + (x2 + vv2[2]);
            x3 = jw2 * wj2[3] + (x3 + vv2[3]);
            x0 = __builtin_elementwise_max(x0, z2);
            x1 = __builtin_elementwise_max(x1, z2);
            x2 = __builtin_elementwise_max(x2, z2);
            x3 = __builtin_elementwise_max(x3, z2);

            union BU { u32x4 u4; bf16x8 v; unsigned int d[4]; } bx;
            bx.d[0] = pkcvt(x0[0], x0[1]);
            bx.d[1] = pkcvt(x1[0], x1[1]);
            bx.d[2] = pkcvt(x2[0], x2[1]);
            bx.d[3] = pkcvt(x3[0], x3[1]);

            f32x4 c0 = __builtin_amdgcn_mfma_f32_16x16x32_bf16(w2a0.v, bx.v, b2v0, 0, 0, 0);
            f32x4 c1 = __builtin_amdgcn_mfma_f32_16x16x32_bf16(w2a1.v, bx.v, b2v1, 0, 0, 0);
            c0 = __builtin_elementwise_max(c0, z4);
            c1 = __builtin_elementwise_max(c1, z4);

#if HAVE_MFMA16
            union B4 { bf16x4 v; unsigned int d[2]; } A0, A1;
            A0.d[0] = pkcvt(c0[0], c0[1]); A0.d[1] = pkcvt(c0[2], c0[3]);
            A1.d[0] = pkcvt(c1[0], c1[1]); A1.d[1] = pkcvt(c1[2], c1[3]);

            f32x4 e0 = MFMA16(A0.v, B0a.v, b3lo);
            e0 = MFMA16(A1.v, B1a.v, e0);
            f32x4 e1 = MFMA16(A0.v, B0b.v, b3hi);
            e1 = MFMA16(A1.v, B1b.v, e1);
            acc0 = acc0 + __builtin_elementwise_max(e0, z4);
            acc1 = acc1 + __builtin_elementwise_max(e1, z4);
#else
            const int d0 = (int)pkcvt(c0[0], c0[1]);
            const int d1 = (int)pkcvt(c0[2], c0[3]);
            const int d2 = (int)pkcvt(c1[0], c1[1]);
            const int d3 = (int)pkcvt(c1[2], c1[3]);
            const int A0_ = __builtin_amdgcn_ds_bpermute(s0, d0);
            const int A1_ = __builtin_amdgcn_ds_bpermute(s0, d1);
            const int A2_ = __builtin_amdgcn_ds_bpermute(s1, d0);
            const int A3_ = __builtin_amdgcn_ds_bpermute(s1, d1);
            const int B0_ = __builtin_amdgcn_ds_bpermute(s0, d2);
            const int B1_ = __builtin_amdgcn_ds_bpermute(s0, d3);
            const int B2_ = __builtin_amdgcn_ds_bpermute(s1, d2);
            const int B3_ = __builtin_amdgcn_ds_bpermute(s1, d3);
            union BU yr;
            yr.d[0] = (unsigned)(qlo ? A0_ : B0_);
            yr.d[1] = (unsigned)(qlo ? A1_ : B1_);
            yr.d[2] = (unsigned)(qlo ? A2_ : B2_);
            yr.d[3] = (unsigned)(qlo ? A3_ : B3_);
            f32x4 e0 = __builtin_amdgcn_mfma_f32_16x16x32_bf16(w3a0.v, yr.v, b3v0, 0, 0, 0);
            f32x4 e1 = __builtin_amdgcn_mfma_f32_16x16x32_bf16(w3a1.v, yr.v, b3v1, 0, 0, 0);
            acc0 = acc0 + __builtin_elementwise_max(e0, z4);
            acc1 = acc1 + __builtin_elementwise_max(e1, z4);
#endif
        }
    }

#if HAVE_MFMA16
    float s0v = acc0[0] + acc0[1] + acc0[2] + acc0[3];
    float s1v = acc1[0] + acc1[1] + acc1[2] + acc1[3];
    s0v += __shfl_xor(s0v, 16);  s0v += __shfl_xor(s0v, 32);
    s1v += __shfl_xor(s1v, 16);  s1v += __shfl_xor(s1v, 32);
    if (l < 16) { red[w * 32 + l] = s0v;  red[w * 32 + 16 + l] = s1v; }
#else
#pragma unroll
    for (int bit = 1; bit < 16; bit <<= 1) {
#pragma unroll
        for (int r = 0; r < 4; r++) {
            acc0[r] += __shfl_xor(acc0[r], bit);
            acc1[r] += __shfl_xor(acc1[r], bit);
        }
    }
    if (p == 0) {
#pragma unroll
        for (int r = 0; r < 4; r++) {
            red[w * 32 + q * 4 + r]      = acc0[r];
            red[w * 32 + 16 + q * 4 + r] = acc1[r];
        }
    }
#endif
    __syncthreads();

    // ---- publish partial, decide tail owner ----
    if (tid < 32)
        mpart[(half << 15) + j * 32 + tid] =
            red[tid] + red[32 + tid] + red[64 + tid] + red[96 + tid];
    __threadfence();                       // release mpart
    if (tid == 0) amSecond = atomicAdd(&flags[j], 1);
    __syncthreads();
    if (amSecond != 1) return;             // first finisher exits
    __threadfence();                       // acquire other half's mpart

    // ---- tail: GRU + u/v refresh (+ readout) ----
    if (tid < 64) {
        float val;
        if (tid < 32) val = h[j * 32 + tid];
        else {
            int s = tid - 32;
            val = mpart[j * 32 + s] + mpart[(1 << 15) + j * 32 + s];
        }
        hm[tid] = val;
    }
    __syncthreads();

    if (tid < 192) {
        const int row = tid >> 1, hh = tid & 1;
        const float* wr = Wih + row * 64 + hh * 32;
        const float* hhp = hm + hh * 32;
        float acc = 0.f;
#pragma unroll
        for (int k4 = 0; k4 < 8; k4++) {
            float4 w4 = *(const float4*)(wr + 4 * k4);
            acc = fmaf(w4.x, hhp[4 * k4 + 0], acc);
            acc = fmaf(w4.y, hhp[4 * k4 + 1], acc);
            acc = fmaf(w4.z, hhp[4 * k4 + 2], acc);
            acc = fmaf(w4.w, hhp[4 * k4 + 3], acc);
        }
        acc += __shfl_xor(acc, 1);
        if (hh == 0) gbuf[row] = acc + bih[row];
    }
    __syncthreads();

    if (tid < 32) {
        const int s = tid;
        float r = sigmoidf_(gbuf[s] + bhh[s]);
        float z = sigmoidf_(gbuf[32 + s] + bhh[32 + s]);
        float n = tanhf(gbuf[64 + s] + r * bhh[64 + s]);
        float hn_ = (1.0f - z) * n;
        hnb[s] = hn_;
        h[j * 32 + s] = hn_;
    }
    __syncthreads();

    if (tid < 64) {
        const int s = tid & 31;
        const bool isV = tid >= 32;
        const float bj = b[j];
        const float* wr = W1 + s * 67 + (isV ? 32 : 0);
        float acc = isV ? fmaf(bj, W1[s * 67 + 66], b1[s]) : bj * W1[s * 67 + 65];
#pragma unroll
        for (int k = 0; k < 32; k++) acc = fmaf(wr[k], hnb[k], acc);
        if (isV) v[j * 32 + s] = acc;
        else     uo[j * 32 + s] = acc;
    }

    if (do_out) {
        __syncthreads();
        if (tid < 32) {
            float a = rb1[tid];
            const float* rr = R1 + tid * 32;
#pragma unroll 8
            for (int k = 0; k < 32; k++) a = fmaf(rr[k], hnb[k], a);
            gbuf[tid] = fmaxf(a, 0.f);
        }
        __syncthreads();
        if (tid < 32) {
            float a = rb2[tid];
            const float* rr = R2 + tid * 32;
#pragma unroll 8
            for (int k = 0; k < 32; k++) a = fmaf(rr[k], gbuf[k], a);
            tb[tid] = fmaxf(a, 0.f);
        }
        __syncthreads();
        if (tid < 2) {
            float a = rb3[tid];
            const float* rr = R3 + tid * 32;
#pragma unroll 8
            for (int k = 0; k < 32; k++) a = fmaf(rr[k], tb[k], a);
            out[j * 2 + tid] = sigmoidf_(fmaxf(a, 0.f));
        }
    }
}

// ---------------------------------------------------------------------------
extern "C" void kernel_launch(void* const* d_in, const int* in_sizes, int n_in,
                              void* d_out, int out_size, void* d_ws, size_t ws_size,
                              hipStream_t stream)
{
    const float* J   = (const float*)d_in[0];
    const float* b   = (const float*)d_in[1];
    const float* W1  = (const float*)d_in[2];
    const float* b1  = (const float*)d_in[3];
    const float* W2  = (const float*)d_in[4];
    const float* b2  = (const float*)d_in[5];
    const float* W3  = (const float*)d_in[6];
    const float* b3  = (const float*)d_in[7];
    const float* Wih = (const float*)d_in[8];
    const float* bih = (const float*)d_in[9];
    const float* bhh = (const float*)d_in[10];
    const float* R1  = (const float*)d_in[11];
    const float* rb1 = (const float*)d_in[12];
    const float* R2  = (const float*)d_in[13];
    const float* rb2 = (const float*)d_in[14];
    const float* R3  = (const float*)d_in[15];
    const float* rb3 = (const float*)d_in[16];

    float* out = (float*)d_out;
    float* ws  = (float*)d_ws;
    float* h     = ws;
    float* v     = ws + 32768;
    float* u0    = ws + 65536;
    float* u1    = ws + 98304;
    float* Jt    = ws + 131072;
    float* cfg   = ws + 131072 + NN * NN;
    float* mpart = cfg + CFG_FLOATS;          // 2 * 32768 floats
    int*   flags = (int*)(mpart + 65536);     // 5 * 1024 ints

    k_pre<<<1154, 256, 0, stream>>>(J, b, W1, b1, W2, b2, W3, b3,
                                    Jt, h, u0, v, cfg, flags);
    for (int s = 0; s < 5; s++) {
        const float* ui = (s & 1) ? u1 : u0;
        float*       uo = (s & 1) ? u0 : u1;
        k_step<<<2048, 256, 0, stream>>>(Jt, cfg, Wih, bih, bhh, b, b1, W1,
                                         R1, rb1, R2, rb2, R3, rb3,
                                         h, v, ui, uo, mpart, flags + s * 1024,
                                         out, (s == 4) ? 1 : 0);
    }
}

// Round 15
// 256.517 us; speedup vs baseline: 9.3458x; 5.0720x over previous
//
#include <hip/hip_runtime.h>
#include <math.h>

#define NN 1024

typedef __attribute__((ext_vector_type(8))) short bf16x8;
typedef __attribute__((ext_vector_type(4))) short bf16x4;
typedef __attribute__((ext_vector_type(4))) float f32x4;
typedef __attribute__((ext_vector_type(2))) float f32x2;
typedef __attribute__((ext_vector_type(4))) unsigned int u32x4;

#if __has_builtin(__builtin_amdgcn_mfma_f32_16x16x16bf16_1k)
#define HAVE_MFMA16 1
#define MFMA16(a, b, c) __builtin_amdgcn_mfma_f32_16x16x16bf16_1k((a), (b), (c), 0, 0, 0)
#else
#define HAVE_MFMA16 0
#endif

__device__ __forceinline__ float sigmoidf_(float x) { return 1.0f / (1.0f + __expf(-x)); }

__device__ __forceinline__ unsigned int pk2(float a, float b) {
    return __builtin_amdgcn_perm(__float_as_uint(a) + 0x8000u,
                                 __float_as_uint(b) + 0x8000u, 0x03020706u);
}
__device__ __forceinline__ unsigned int pkcvt(float a, float b) {
#if __has_builtin(__builtin_amdgcn_cvt_pk_bf16_f32)
    return __builtin_bit_cast(unsigned int, __builtin_amdgcn_cvt_pk_bf16_f32(a, b));
#else
    return pk2(a, b);
#endif
}
__device__ __forceinline__ unsigned short f2bf_rne(float a) {
    unsigned int ua = __float_as_uint(a);
    ua += 0x7fffu + ((ua >> 16) & 1u);
    return (unsigned short)(ua >> 16);
}
__device__ __forceinline__ unsigned int pk2b(float a, float b) {
    return (unsigned int)f2bf_rne(a) | ((unsigned int)f2bf_rne(b) << 16);
}

#define CFG_FLOATS 3584

// ---------------------------------------------------------------------------
// k_pre: blocks 0..1023 transpose J -> Jt; 1024..1151 init h,u0,v;
//        block 1152 precomputes per-lane MFMA context into cfg.
// ---------------------------------------------------------------------------
__global__ __launch_bounds__(256) void k_pre(
    const float* __restrict__ J, const float* __restrict__ b,
    const float* __restrict__ W1, const float* __restrict__ b1,
    const float* __restrict__ W2, const float* __restrict__ b2,
    const float* __restrict__ W3, const float* __restrict__ b3,
    float* __restrict__ Jt, float* __restrict__ h,
    float* __restrict__ u0, float* __restrict__ v, float* __restrict__ cfg)
{
    __shared__ float tile[32][33];
    const int t = blockIdx.x;
    const int tid = threadIdx.x;
    if (t < 1024) {
        int tx = (t & 31) * 32, ty = (t >> 5) * 32;
        int x = tid & 31, y = tid >> 5;
#pragma unroll
        for (int r = 0; r < 4; r++)
            tile[y + 8 * r][x] = J[(size_t)(ty + y + 8 * r) * NN + tx + x];
        __syncthreads();
#pragma unroll
        for (int r = 0; r < 4; r++)
            Jt[(size_t)(tx + y + 8 * r) * NN + ty + x] = tile[x][y + 8 * r];
    } else if (t < 1152) {
        int idx = (t - 1024) * 256 + tid;
        int row = idx >> 5, mm = idx & 31;
        float bi = b[row];
        h[idx]  = 0.f;
        u0[idx] = bi * W1[mm * 67 + 65];
        v[idx]  = fmaf(bi, W1[mm * 67 + 66], b1[mm]);
    } else if (tid < 64) {
        const int l = tid, p = l & 15, q = l >> 4;
        union FU { unsigned int d[4]; unsigned short s[8]; } t0, t1, t2, t3;
        float wj[8];
#pragma unroll
        for (int jj = 0; jj < 8; jj++) {
            int k = q * 8 + jj;
            t0.s[jj] = f2bf_rne(W2[p * 32 + k]);
            t1.s[jj] = f2bf_rne(W2[(16 + p) * 32 + k]);
            t2.s[jj] = f2bf_rne(W3[p * 32 + k]);
            t3.s[jj] = f2bf_rne(W3[(16 + p) * 32 + k]);
            wj[jj] = W1[k * 67 + 64];
        }
        u32x4* cw = (u32x4*)cfg;
        cw[l]       = *(u32x4*)t0.d;
        cw[64 + l]  = *(u32x4*)t1.d;
        cw[128 + l] = *(u32x4*)t2.d;
        cw[192 + l] = *(u32x4*)t3.d;
        f32x4* cf = (f32x4*)(cfg + 1024);
        f32x4 v0, v1, v2, v3;
#pragma unroll
        for (int r = 0; r < 4; r++) {
            v0[r] = b2[q * 4 + r];  v1[r] = b2[16 + q * 4 + r];
            v2[r] = b3[q * 4 + r];  v3[r] = b3[16 + q * 4 + r];
        }
        cf[l] = v0; cf[64 + l] = v1; cf[128 + l] = v2; cf[192 + l] = v3;
        f32x4* cj = (f32x4*)(cfg + 2048);
        f32x4 wlo, whi;
#pragma unroll
        for (int r = 0; r < 4; r++) { wlo[r] = wj[r]; whi[r] = wj[4 + r]; }
        cj[l] = wlo; cj[64 + l] = whi;

        const int g = p;
        u32x4 fa, fb;
        fa[0] = pk2b(W3[g * 32 + 4 * q + 0],      W3[g * 32 + 4 * q + 1]);
        fa[1] = pk2b(W3[g * 32 + 4 * q + 2],      W3[g * 32 + 4 * q + 3]);
        fa[2] = pk2b(W3[g * 32 + 16 + 4 * q + 0], W3[g * 32 + 16 + 4 * q + 1]);
        fa[3] = pk2b(W3[g * 32 + 16 + 4 * q + 2], W3[g * 32 + 16 + 4 * q + 3]);
        fb[0] = pk2b(W3[(16 + g) * 32 + 4 * q + 0],      W3[(16 + g) * 32 + 4 * q + 1]);
        fb[1] = pk2b(W3[(16 + g) * 32 + 4 * q + 2],      W3[(16 + g) * 32 + 4 * q + 3]);
        fb[2] = pk2b(W3[(16 + g) * 32 + 16 + 4 * q + 0], W3[(16 + g) * 32 + 16 + 4 * q + 1]);
        fb[3] = pk2b(W3[(16 + g) * 32 + 16 + 4 * q + 2], W3[(16 + g) * 32 + 16 + 4 * q + 3]);
        u32x4* cw2 = (u32x4*)(cfg + 2560);
        cw2[l] = fa; cw2[64 + l] = fb;
        f32x4* cb3 = (f32x4*)(cfg + 3072);
        f32x4 r0, r1;
#pragma unroll
        for (int r = 0; r < 4; r++) { r0[r] = b3[g]; r1[r] = b3[16 + g]; }
        cb3[l] = r0; cb3[64 + l] = r1;
    }
}

// ---------------------------------------------------------------------------
// k_step: one recurrence step, tail fused.  Grid 1024 (one block per j),
// 512 threads = 8 waves, each wave 4 pairs (8 tiles) -> 1024 i's total.
// 1024 blocks x 8 waves = 32 waves/CU at VGPR<=64 (4 blocks/CU) — the
// fence-free occupancy-doubling vs r12's 256-thread blocks.  No forced
// min-waves bound (r13 lesson); no cross-block coordination (r14 lesson).
// ---------------------------------------------------------------------------
__global__ __launch_bounds__(512) void k_step(
    const float* __restrict__ Jt, const float* __restrict__ cfg,
    const float* __restrict__ Wih, const float* __restrict__ bih,
    const float* __restrict__ bhh, const float* __restrict__ b,
    const float* __restrict__ b1, const float* __restrict__ W1,
    const float* __restrict__ R1, const float* __restrict__ rb1,
    const float* __restrict__ R2, const float* __restrict__ rb2,
    const float* __restrict__ R3, const float* __restrict__ rb3,
    float* __restrict__ h, float* __restrict__ v,
    const float* __restrict__ ui, float* __restrict__ uo,
    float* __restrict__ out, int do_out)
{
    __shared__ float red[8 * 32];
    __shared__ float hm[64], gbuf[96], hnb[32], tb[32];

    const int tid = threadIdx.x;
    const int w = tid >> 6;        // 0..7
    const int l = tid & 63;
    const int p = l & 15;
    const int q = l >> 4;
    const int j = blockIdx.x;

    union FU { bf16x8 v; u32x4 u4; } w2a0, w2a1;
    const u32x4* cw = (const u32x4*)cfg;
    w2a0.u4 = cw[l]; w2a1.u4 = cw[64 + l];
    const f32x4* cf = (const f32x4*)(cfg + 1024);
    const f32x4 b2v0 = cf[l], b2v1 = cf[64 + l];
    const f32x4* cj = (const f32x4*)(cfg + 2048);
    const f32x4 wlo = cj[l], whi = cj[64 + l];
    f32x2 wj2[4] = { {wlo[0], wlo[1]}, {wlo[2], wlo[3]}, {whi[0], whi[1]}, {whi[2], whi[3]} };

#if HAVE_MFMA16
    union B4 { bf16x4 v; unsigned int d[2]; } B0a, B1a, B0b, B1b;
    {
        const u32x4* cw2 = (const u32x4*)(cfg + 2560);
        u32x4 fa = cw2[l], fb = cw2[64 + l];
        B0a.d[0] = fa[0]; B0a.d[1] = fa[1]; B1a.d[0] = fa[2]; B1a.d[1] = fa[3];
        B0b.d[0] = fb[0]; B0b.d[1] = fb[1]; B1b.d[0] = fb[2]; B1b.d[1] = fb[3];
    }
    const f32x4* cb3 = (const f32x4*)(cfg + 3072);
    const f32x4 b3lo = cb3[l], b3hi = cb3[64 + l];
#else
    union FU w3a0, w3a1;
    w3a0.u4 = cw[128 + l]; w3a1.u4 = cw[192 + l];
    const f32x4 b3v0 = cf[128 + l], b3v1 = cf[192 + l];
    const int s0 = (p | ((l & 16) << 1)) << 2;
    const int s1 = s0 + 64;
    const bool qlo = (l & 32) == 0;
#endif

    f32x2 vv2[4];
    {
        float4 va = *(const float4*)(v + j * 32 + q * 8);
        float4 vb = *(const float4*)(v + j * 32 + q * 8 + 4);
        vv2[0] = f32x2{va.x, va.y}; vv2[1] = f32x2{va.z, va.w};
        vv2[2] = f32x2{vb.x, vb.y}; vv2[3] = f32x2{vb.z, vb.w};
    }

    f32x4 acc0 = {0.f, 0.f, 0.f, 0.f}, acc1 = {0.f, 0.f, 0.f, 0.f};

    // ---- 4 pairs (8 tiles) per wave, depth-2 pair prefetch ----
    const int ibase = w * 128;
    const float* jp = Jt + (size_t)j * NN + ibase + p;
    const float* up = ui + (size_t)(ibase + p) * 32 + q * 8;

    float  jw0[2], jw1[2];
    float4 ua0[2], ub0[2], ua1[2], ub1[2];
#pragma unroll
    for (int s = 0; s < 2; s++) {
        jw0[s] = jp[s * 32];       jw1[s] = jp[s * 32 + 16];
        ua0[s] = *(const float4*)(up + (size_t)s * 1024);
        ub0[s] = *(const float4*)(up + (size_t)s * 1024 + 4);
        ua1[s] = *(const float4*)(up + (size_t)s * 1024 + 512);
        ub1[s] = *(const float4*)(up + (size_t)s * 1024 + 516);
    }

#pragma unroll
    for (int tt = 0; tt < 4; ++tt) {
        const int sl = tt & 1;
        const float  jwA_c = jw0[sl], jwB_c = jw1[sl];
        const float4 uaA_c = ua0[sl], ubA_c = ub0[sl];
        const float4 uaB_c = ua1[sl], ubB_c = ub1[sl];
        if (tt < 2) {
            const float* jn = jp + (tt + 2) * 32;
            const float* un = up + (size_t)(tt + 2) * 1024;
            jw0[sl] = jn[0];  jw1[sl] = jn[16];
            ua0[sl] = *(const float4*)(un);
            ub0[sl] = *(const float4*)(un + 4);
            ua1[sl] = *(const float4*)(un + 512);
            ub1[sl] = *(const float4*)(un + 516);
        }

#pragma unroll
        for (int hh2 = 0; hh2 < 2; ++hh2) {
            const float  jw = hh2 ? jwB_c : jwA_c;
            const float4 ua_c = hh2 ? uaB_c : uaA_c;
            const float4 ub_c = hh2 ? ubB_c : ubA_c;

            const f32x2 jw2 = {jw, jw};
            const f32x2 z2 = {0.f, 0.f};
            const f32x4 z4 = {0.f, 0.f, 0.f, 0.f};

            f32x2 x0 = {ua_c.x, ua_c.y}, x1 = {ua_c.z, ua_c.w};
            f32x2 x2 = {ub_c.x, ub_c.y}, x3 = {ub_c.z, ub_c.w};
            x0 = jw2 * wj2[0] + (x0 + vv2[0]);
            x1 = jw2 * wj2[1] + (x1 + vv2[1]);
            x2 = jw2 * wj2[2] + (x2 + vv2[2]);
            x3 = jw2 * wj2[3] + (x3 + vv2[3]);
            x0 = __builtin_elementwise_max(x0, z2);
            x1 = __builtin_elementwise_max(x1, z2);
            x2 = __builtin_elementwise_max(x2, z2);
            x3 = __builtin_elementwise_max(x3, z2);

            union BU { u32x4 u4; bf16x8 v; unsigned int d[4]; } bx;
            bx.d[0] = pkcvt(x0[0], x0[1]);
            bx.d[1] = pkcvt(x1[0], x1[1]);
            bx.d[2] = pkcvt(x2[0], x2[1]);
            bx.d[3] = pkcvt(x3[0], x3[1]);

            f32x4 c0 = __builtin_amdgcn_mfma_f32_16x16x32_bf16(w2a0.v, bx.v, b2v0, 0, 0, 0);
            f32x4 c1 = __builtin_amdgcn_mfma_f32_16x16x32_bf16(w2a1.v, bx.v, b2v1, 0, 0, 0);
            c0 = __builtin_elementwise_max(c0, z4);
            c1 = __builtin_elementwise_max(c1, z4);

#if HAVE_MFMA16
            union B4 { bf16x4 v; unsigned int d[2]; } A0, A1;
            A0.d[0] = pkcvt(c0[0], c0[1]); A0.d[1] = pkcvt(c0[2], c0[3]);
            A1.d[0] = pkcvt(c1[0], c1[1]); A1.d[1] = pkcvt(c1[2], c1[3]);

            f32x4 e0 = MFMA16(A0.v, B0a.v, b3lo);
            e0 = MFMA16(A1.v, B1a.v, e0);
            f32x4 e1 = MFMA16(A0.v, B0b.v, b3hi);
            e1 = MFMA16(A1.v, B1b.v, e1);
            acc0 = acc0 + __builtin_elementwise_max(e0, z4);
            acc1 = acc1 + __builtin_elementwise_max(e1, z4);
#else
            const int d0 = (int)pkcvt(c0[0], c0[1]);
            const int d1 = (int)pkcvt(c0[2], c0[3]);
            const int d2 = (int)pkcvt(c1[0], c1[1]);
            const int d3 = (int)pkcvt(c1[2], c1[3]);
            const int A0_ = __builtin_amdgcn_ds_bpermute(s0, d0);
            const int A1_ = __builtin_amdgcn_ds_bpermute(s0, d1);
            const int A2_ = __builtin_amdgcn_ds_bpermute(s1, d0);
            const int A3_ = __builtin_amdgcn_ds_bpermute(s1, d1);
            const int B0_ = __builtin_amdgcn_ds_bpermute(s0, d2);
            const int B1_ = __builtin_amdgcn_ds_bpermute(s0, d3);
            const int B2_ = __builtin_amdgcn_ds_bpermute(s1, d2);
            const int B3_ = __builtin_amdgcn_ds_bpermute(s1, d3);
            union BU yr;
            yr.d[0] = (unsigned)(qlo ? A0_ : B0_);
            yr.d[1] = (unsigned)(qlo ? A1_ : B1_);
            yr.d[2] = (unsigned)(qlo ? A2_ : B2_);
            yr.d[3] = (unsigned)(qlo ? A3_ : B3_);
            f32x4 e0 = __builtin_amdgcn_mfma_f32_16x16x32_bf16(w3a0.v, yr.v, b3v0, 0, 0, 0);
            f32x4 e1 = __builtin_amdgcn_mfma_f32_16x16x32_bf16(w3a1.v, yr.v, b3v1, 0, 0, 0);
            acc0 = acc0 + __builtin_elementwise_max(e0, z4);
            acc1 = acc1 + __builtin_elementwise_max(e1, z4);
#endif
        }
    }

#if HAVE_MFMA16
    float s0v = acc0[0] + acc0[1] + acc0[2] + acc0[3];
    float s1v = acc1[0] + acc1[1] + acc1[2] + acc1[3];
    s0v += __shfl_xor(s0v, 16);  s0v += __shfl_xor(s0v, 32);
    s1v += __shfl_xor(s1v, 16);  s1v += __shfl_xor(s1v, 32);
    if (l < 16) { red[w * 32 + l] = s0v;  red[w * 32 + 16 + l] = s1v; }
#else
#pragma unroll
    for (int bit = 1; bit < 16; bit <<= 1) {
#pragma unroll
        for (int r = 0; r < 4; r++) {
            acc0[r] += __shfl_xor(acc0[r], bit);
            acc1[r] += __shfl_xor(acc1[r], bit);
        }
    }
    if (p == 0) {
#pragma unroll
        for (int r = 0; r < 4; r++) {
            red[w * 32 + q * 4 + r]      = acc0[r];
            red[w * 32 + 16 + q * 4 + r] = acc1[r];
        }
    }
#endif
    __syncthreads();

    // ---- tail: GRU + u/v refresh (+ readout) ----
    if (tid < 64) {
        float val;
        if (tid < 32) val = h[j * 32 + tid];
        else {
            int s = tid - 32;
            val = red[s] + red[32 + s] + red[64 + s] + red[96 + s]
                + red[128 + s] + red[160 + s] + red[192 + s] + red[224 + s];
        }
        hm[tid] = val;
    }
    __syncthreads();

    if (tid < 192) {
        const int row = tid >> 1, hh = tid & 1;
        const float* wr = Wih + row * 64 + hh * 32;
        const float* hhp = hm + hh * 32;
        float acc = 0.f;
#pragma unroll
        for (int k4 = 0; k4 < 8; k4++) {
            float4 w4 = *(const float4*)(wr + 4 * k4);
            acc = fmaf(w4.x, hhp[4 * k4 + 0], acc);
            acc = fmaf(w4.y, hhp[4 * k4 + 1], acc);
            acc = fmaf(w4.z, hhp[4 * k4 + 2], acc);
            acc = fmaf(w4.w, hhp[4 * k4 + 3], acc);
        }
        acc += __shfl_xor(acc, 1);
        if (hh == 0) gbuf[row] = acc + bih[row];
    }
    __syncthreads();

    if (tid < 32) {
        const int s = tid;
        float r = sigmoidf_(gbuf[s] + bhh[s]);
        float z = sigmoidf_(gbuf[32 + s] + bhh[32 + s]);
        float n = tanhf(gbuf[64 + s] + r * bhh[64 + s]);
        float hn_ = (1.0f - z) * n;
        hnb[s] = hn_;
        h[j * 32 + s] = hn_;
    }
    __syncthreads();

    if (tid < 64) {
        const int s = tid & 31;
        const bool isV = tid >= 32;
        const float bj = b[j];
        const float* wr = W1 + s * 67 + (isV ? 32 : 0);
        float acc = isV ? fmaf(bj, W1[s * 67 + 66], b1[s]) : bj * W1[s * 67 + 65];
#pragma unroll
        for (int k = 0; k < 32; k++) acc = fmaf(wr[k], hnb[k], acc);
        if (isV) v[j * 32 + s] = acc;
        else     uo[j * 32 + s] = acc;
    }

    if (do_out) {
        __syncthreads();
        if (tid < 32) {
            float a = rb1[tid];
            const float* rr = R1 + tid * 32;
#pragma unroll 8
            for (int k = 0; k < 32; k++) a = fmaf(rr[k], hnb[k], a);
            gbuf[tid] = fmaxf(a, 0.f);
        }
        __syncthreads();
        if (tid < 32) {
            float a = rb2[tid];
            const float* rr = R2 + tid * 32;
#pragma unroll 8
            for (int k = 0; k < 32; k++) a = fmaf(rr[k], gbuf[k], a);
            tb[tid] = fmaxf(a, 0.f);
        }
        __syncthreads();
        if (tid < 2) {
            float a = rb3[tid];
            const float* rr = R3 + tid * 32;
#pragma unroll 8
            for (int k = 0; k < 32; k++) a = fmaf(rr[k], tb[k], a);
            out[j * 2 + tid] = sigmoidf_(fmaxf(a, 0.f));
        }
    }
}

// ---------------------------------------------------------------------------
extern "C" void kernel_launch(void* const* d_in, const int* in_sizes, int n_in,
                              void* d_out, int out_size, void* d_ws, size_t ws_size,
                              hipStream_t stream)
{
    const float* J   = (const float*)d_in[0];
    const float* b   = (const float*)d_in[1];
    const float* W1  = (const float*)d_in[2];
    const float* b1  = (const float*)d_in[3];
    const float* W2  = (const float*)d_in[4];
    const float* b2  = (const float*)d_in[5];
    const float* W3  = (const float*)d_in[6];
    const float* b3  = (const float*)d_in[7];
    const float* Wih = (const float*)d_in[8];
    const float* bih = (const float*)d_in[9];
    const float* bhh = (const float*)d_in[10];
    const float* R1  = (const float*)d_in[11];
    const float* rb1 = (const float*)d_in[12];
    const float* R2  = (const float*)d_in[13];
    const float* rb2 = (const float*)d_in[14];
    const float* R3  = (const float*)d_in[15];
    const float* rb3 = (const float*)d_in[16];

    float* out = (float*)d_out;
    float* ws  = (float*)d_ws;
    float* h   = ws;
    float* v   = ws + 32768;
    float* u0  = ws + 65536;
    float* u1  = ws + 98304;
    float* Jt  = ws + 131072;
    float* cfg = ws + 131072 + NN * NN;

    k_pre<<<1153, 256, 0, stream>>>(J, b, W1, b1, W2, b2, W3, b3,
                                    Jt, h, u0, v, cfg);
    for (int s = 0; s < 5; s++) {
        const float* ui = (s & 1) ? u1 : u0;
        float*       uo = (s & 1) ? u0 : u1;
        k_step<<<1024, 512, 0, stream>>>(Jt, cfg, Wih, bih, bhh, b, b1, W1,
                                         R1, rb1, R2, rb2, R3, rb3,
                                         h, v, ui, uo, out, (s == 4) ? 1 : 0);
    }
}

// Round 16
// 230.357 us; speedup vs baseline: 10.4072x; 1.1136x over previous
//
#include <hip/hip_runtime.h>
#include <math.h>

#define NN 1024

typedef __attribute__((ext_vector_type(8))) short bf16x8;
typedef __attribute__((ext_vector_type(4))) short bf16x4;
typedef __attribute__((ext_vector_type(4))) float f32x4;
typedef __attribute__((ext_vector_type(2))) float f32x2;
typedef __attribute__((ext_vector_type(4))) unsigned int u32x4;

#if __has_builtin(__builtin_amdgcn_mfma_f32_16x16x16bf16_1k)
#define HAVE_MFMA16 1
#define MFMA16(a, b, c) __builtin_amdgcn_mfma_f32_16x16x16bf16_1k((a), (b), (c), 0, 0, 0)
#else
#define HAVE_MFMA16 0
#endif

__device__ __forceinline__ float sigmoidf_(float x) { return 1.0f / (1.0f + __expf(-x)); }

__device__ __forceinline__ unsigned int pk2(float a, float b) {
    return __builtin_amdgcn_perm(__float_as_uint(a) + 0x8000u,
                                 __float_as_uint(b) + 0x8000u, 0x03020706u);
}
__device__ __forceinline__ unsigned int pkcvt(float a, float b) {
#if __has_builtin(__builtin_amdgcn_cvt_pk_bf16_f32)
    return __builtin_bit_cast(unsigned int, __builtin_amdgcn_cvt_pk_bf16_f32(a, b));
#else
    return pk2(a, b);
#endif
}
__device__ __forceinline__ unsigned short f2bf_rne(float a) {
    unsigned int ua = __float_as_uint(a);
    ua += 0x7fffu + ((ua >> 16) & 1u);
    return (unsigned short)(ua >> 16);
}
__device__ __forceinline__ unsigned int pk2b(float a, float b) {
    return (unsigned int)f2bf_rne(a) | ((unsigned int)f2bf_rne(b) << 16);
}

#define CFG_FLOATS 3584

// ---------------------------------------------------------------------------
// k_pre: blocks 0..127 init h,u0,v; block 128 precomputes per-lane MFMA
// context into cfg.  (No J transpose anymore: k_step stages its J column
// into LDS directly.)
// ---------------------------------------------------------------------------
__global__ __launch_bounds__(256) void k_pre(
    const float* __restrict__ b,
    const float* __restrict__ W1, const float* __restrict__ b1,
    const float* __restrict__ W2, const float* __restrict__ b2,
    const float* __restrict__ W3, const float* __restrict__ b3,
    float* __restrict__ h, float* __restrict__ u0, float* __restrict__ v,
    float* __restrict__ cfg)
{
    const int t = blockIdx.x;
    const int tid = threadIdx.x;
    if (t < 128) {
        int idx = t * 256 + tid;           // 0..32767
        int row = idx >> 5, mm = idx & 31;
        float bi = b[row];
        h[idx]  = 0.f;
        u0[idx] = bi * W1[mm * 67 + 65];
        v[idx]  = fmaf(bi, W1[mm * 67 + 66], b1[mm]);
    } else if (tid < 64) {
        const int l = tid, p = l & 15, q = l >> 4;
        union FU { unsigned int d[4]; unsigned short s[8]; } t0, t1, t2, t3;
        float wj[8];
#pragma unroll
        for (int jj = 0; jj < 8; jj++) {
            int k = q * 8 + jj;
            t0.s[jj] = f2bf_rne(W2[p * 32 + k]);
            t1.s[jj] = f2bf_rne(W2[(16 + p) * 32 + k]);
            t2.s[jj] = f2bf_rne(W3[p * 32 + k]);
            t3.s[jj] = f2bf_rne(W3[(16 + p) * 32 + k]);
            wj[jj] = W1[k * 67 + 64];
        }
        u32x4* cw = (u32x4*)cfg;
        cw[l]       = *(u32x4*)t0.d;
        cw[64 + l]  = *(u32x4*)t1.d;
        cw[128 + l] = *(u32x4*)t2.d;
        cw[192 + l] = *(u32x4*)t3.d;
        f32x4* cf = (f32x4*)(cfg + 1024);
        f32x4 v0, v1, v2, v3;
#pragma unroll
        for (int r = 0; r < 4; r++) {
            v0[r] = b2[q * 4 + r];  v1[r] = b2[16 + q * 4 + r];
            v2[r] = b3[q * 4 + r];  v3[r] = b3[16 + q * 4 + r];
        }
        cf[l] = v0; cf[64 + l] = v1; cf[128 + l] = v2; cf[192 + l] = v3;
        f32x4* cj = (f32x4*)(cfg + 2048);
        f32x4 wlo, whi;
#pragma unroll
        for (int r = 0; r < 4; r++) { wlo[r] = wj[r]; whi[r] = wj[4 + r]; }
        cj[l] = wlo; cj[64 + l] = whi;

        const int g = p;
        u32x4 fa, fb;
        fa[0] = pk2b(W3[g * 32 + 4 * q + 0],      W3[g * 32 + 4 * q + 1]);
        fa[1] = pk2b(W3[g * 32 + 4 * q + 2],      W3[g * 32 + 4 * q + 3]);
        fa[2] = pk2b(W3[g * 32 + 16 + 4 * q + 0], W3[g * 32 + 16 + 4 * q + 1]);
        fa[3] = pk2b(W3[g * 32 + 16 + 4 * q + 2], W3[g * 32 + 16 + 4 * q + 3]);
        fb[0] = pk2b(W3[(16 + g) * 32 + 4 * q + 0],      W3[(16 + g) * 32 + 4 * q + 1]);
        fb[1] = pk2b(W3[(16 + g) * 32 + 4 * q + 2],      W3[(16 + g) * 32 + 4 * q + 3]);
        fb[2] = pk2b(W3[(16 + g) * 32 + 16 + 4 * q + 0], W3[(16 + g) * 32 + 16 + 4 * q + 1]);
        fb[3] = pk2b(W3[(16 + g) * 32 + 16 + 4 * q + 2], W3[(16 + g) * 32 + 16 + 4 * q + 3]);
        u32x4* cw2 = (u32x4*)(cfg + 2560);
        cw2[l] = fa; cw2[64 + l] = fb;
        f32x4* cb3 = (f32x4*)(cfg + 3072);
        f32x4 r0, r1;
#pragma unroll
        for (int r = 0; r < 4; r++) { r0[r] = b3[g]; r1[r] = b3[16 + g]; }
        cb3[l] = r0; cb3[64 + l] = r1;
    }
}

// ---------------------------------------------------------------------------
// k_step: one recurrence step, tail fused (r12 structure, best known).
// 1024 blocks x 256 threads, 4 waves x 8 pairs.  J column staged into LDS
// at block start (scattered L2/L3 reads, replaces the Jt transpose launch);
// main-loop jw reads come from LDS (conflict-free, broadcast across q).
// ---------------------------------------------------------------------------
__global__ __launch_bounds__(256, 4) void k_step(
    const float* __restrict__ J, const float* __restrict__ cfg,
    const float* __restrict__ Wih, const float* __restrict__ bih,
    const float* __restrict__ bhh, const float* __restrict__ b,
    const float* __restrict__ b1, const float* __restrict__ W1,
    const float* __restrict__ R1, const float* __restrict__ rb1,
    const float* __restrict__ R2, const float* __restrict__ rb2,
    const float* __restrict__ R3, const float* __restrict__ rb3,
    float* __restrict__ h, float* __restrict__ v,
    const float* __restrict__ ui, float* __restrict__ uo,
    float* __restrict__ out, int do_out)
{
    __shared__ float Jrow[NN];     // this block's J[:, j], 4 KB
    __shared__ float red[4 * 32];
    __shared__ float hm[64], gbuf[96], hnb[32], tb[32];

    const int tid = threadIdx.x;
    const int w = tid >> 6;
    const int l = tid & 63;
    const int p = l & 15;
    const int q = l >> 4;
    const int j = blockIdx.x;

    // ---- stage J column (scattered, L3-hit after step 0) ----
#pragma unroll
    for (int r = 0; r < 4; r++)
        Jrow[tid + 256 * r] = J[(size_t)(tid + 256 * r) * NN + j];

    // ---- coalesced per-lane context ----
    union FU { bf16x8 v; u32x4 u4; } w2a0, w2a1;
    const u32x4* cw = (const u32x4*)cfg;
    w2a0.u4 = cw[l]; w2a1.u4 = cw[64 + l];
    const f32x4* cf = (const f32x4*)(cfg + 1024);
    const f32x4 b2v0 = cf[l], b2v1 = cf[64 + l];
    const f32x4* cj = (const f32x4*)(cfg + 2048);
    const f32x4 wlo = cj[l], whi = cj[64 + l];
    f32x2 wj2[4] = { {wlo[0], wlo[1]}, {wlo[2], wlo[3]}, {whi[0], whi[1]}, {whi[2], whi[3]} };

#if HAVE_MFMA16
    union B4 { bf16x4 v; unsigned int d[2]; } B0a, B1a, B0b, B1b;
    {
        const u32x4* cw2 = (const u32x4*)(cfg + 2560);
        u32x4 fa = cw2[l], fb = cw2[64 + l];
        B0a.d[0] = fa[0]; B0a.d[1] = fa[1]; B1a.d[0] = fa[2]; B1a.d[1] = fa[3];
        B0b.d[0] = fb[0]; B0b.d[1] = fb[1]; B1b.d[0] = fb[2]; B1b.d[1] = fb[3];
    }
    const f32x4* cb3 = (const f32x4*)(cfg + 3072);
    const f32x4 b3lo = cb3[l], b3hi = cb3[64 + l];
#else
    union FU w3a0, w3a1;
    w3a0.u4 = cw[128 + l]; w3a1.u4 = cw[192 + l];
    const f32x4 b3v0 = cf[128 + l], b3v1 = cf[192 + l];
    const int s0 = (p | ((l & 16) << 1)) << 2;
    const int s1 = s0 + 64;
    const bool qlo = (l & 32) == 0;
#endif

    f32x2 vv2[4];
    {
        float4 va = *(const float4*)(v + j * 32 + q * 8);
        float4 vb = *(const float4*)(v + j * 32 + q * 8 + 4);
        vv2[0] = f32x2{va.x, va.y}; vv2[1] = f32x2{va.z, va.w};
        vv2[2] = f32x2{vb.x, vb.y}; vv2[3] = f32x2{vb.z, vb.w};
    }

    f32x4 acc0 = {0.f, 0.f, 0.f, 0.f}, acc1 = {0.f, 0.f, 0.f, 0.f};

    // wait for Jrow staging before the main loop reads it
    __syncthreads();

    // ---- 8 pairs (16 tiles) per wave, depth-2 pair prefetch of u ----
    const int ibase = w * 256;
    const float* up = ui + (size_t)(ibase + p) * 32 + q * 8;

    float4 ua0[2], ub0[2], ua1[2], ub1[2];
#pragma unroll
    for (int s = 0; s < 2; s++) {
        ua0[s] = *(const float4*)(up + (size_t)s * 1024);
        ub0[s] = *(const float4*)(up + (size_t)s * 1024 + 4);
        ua1[s] = *(const float4*)(up + (size_t)s * 1024 + 512);
        ub1[s] = *(const float4*)(up + (size_t)s * 1024 + 516);
    }

#pragma unroll
    for (int tt = 0; tt < 8; ++tt) {
        const int sl = tt & 1;
        const float4 uaA_c = ua0[sl], ubA_c = ub0[sl];
        const float4 uaB_c = ua1[sl], ubB_c = ub1[sl];
        const float jwA_c = Jrow[ibase + tt * 32 + p];
        const float jwB_c = Jrow[ibase + tt * 32 + 16 + p];
        if (tt < 6) {
            const float* un = up + (size_t)(tt + 2) * 1024;
            ua0[sl] = *(const float4*)(un);
            ub0[sl] = *(const float4*)(un + 4);
            ua1[sl] = *(const float4*)(un + 512);
            ub1[sl] = *(const float4*)(un + 516);
        }

#pragma unroll
        for (int hh2 = 0; hh2 < 2; ++hh2) {
            const float  jw = hh2 ? jwB_c : jwA_c;
            const float4 ua_c = hh2 ? uaB_c : uaA_c;
            const float4 ub_c = hh2 ? ubB_c : ubA_c;

            const f32x2 jw2 = {jw, jw};
            const f32x2 z2 = {0.f, 0.f};
            const f32x4 z4 = {0.f, 0.f, 0.f, 0.f};

            f32x2 x0 = {ua_c.x, ua_c.y}, x1 = {ua_c.z, ua_c.w};
            f32x2 x2 = {ub_c.x, ub_c.y}, x3 = {ub_c.z, ub_c.w};
            x0 = jw2 * wj2[0] + (x0 + vv2[0]);
            x1 = jw2 * wj2[1] + (x1 + vv2[1]);
            x2 = jw2 * wj2[2] + (x2 + vv2[2]);
            x3 = jw2 * wj2[3] + (x3 + vv2[3]);
            x0 = __builtin_elementwise_max(x0, z2);
            x1 = __builtin_elementwise_max(x1, z2);
            x2 = __builtin_elementwise_max(x2, z2);
            x3 = __builtin_elementwise_max(x3, z2);

            union BU { u32x4 u4; bf16x8 v; unsigned int d[4]; } bx;
            bx.d[0] = pkcvt(x0[0], x0[1]);
            bx.d[1] = pkcvt(x1[0], x1[1]);
            bx.d[2] = pkcvt(x2[0], x2[1]);
            bx.d[3] = pkcvt(x3[0], x3[1]);

            f32x4 c0 = __builtin_amdgcn_mfma_f32_16x16x32_bf16(w2a0.v, bx.v, b2v0, 0, 0, 0);
            f32x4 c1 = __builtin_amdgcn_mfma_f32_16x16x32_bf16(w2a1.v, bx.v, b2v1, 0, 0, 0);
            c0 = __builtin_elementwise_max(c0, z4);
            c1 = __builtin_elementwise_max(c1, z4);

#if HAVE_MFMA16
            union B4 { bf16x4 v; unsigned int d[2]; } A0, A1;
            A0.d[0] = pkcvt(c0[0], c0[1]); A0.d[1] = pkcvt(c0[2], c0[3]);
            A1.d[0] = pkcvt(c1[0], c1[1]); A1.d[1] = pkcvt(c1[2], c1[3]);

            f32x4 e0 = MFMA16(A0.v, B0a.v, b3lo);
            e0 = MFMA16(A1.v, B1a.v, e0);
            f32x4 e1 = MFMA16(A0.v, B0b.v, b3hi);
            e1 = MFMA16(A1.v, B1b.v, e1);
            acc0 = acc0 + __builtin_elementwise_max(e0, z4);
            acc1 = acc1 + __builtin_elementwise_max(e1, z4);
#else
            const int d0 = (int)pkcvt(c0[0], c0[1]);
            const int d1 = (int)pkcvt(c0[2], c0[3]);
            const int d2 = (int)pkcvt(c1[0], c1[1]);
            const int d3 = (int)pkcvt(c1[2], c1[3]);
            const int A0_ = __builtin_amdgcn_ds_bpermute(s0, d0);
            const int A1_ = __builtin_amdgcn_ds_bpermute(s0, d1);
            const int A2_ = __builtin_amdgcn_ds_bpermute(s1, d0);
            const int A3_ = __builtin_amdgcn_ds_bpermute(s1, d1);
            const int B0_ = __builtin_amdgcn_ds_bpermute(s0, d2);
            const int B1_ = __builtin_amdgcn_ds_bpermute(s0, d3);
            const int B2_ = __builtin_amdgcn_ds_bpermute(s1, d2);
            const int B3_ = __builtin_amdgcn_ds_bpermute(s1, d3);
            union BU yr;
            yr.d[0] = (unsigned)(qlo ? A0_ : B0_);
            yr.d[1] = (unsigned)(qlo ? A1_ : B1_);
            yr.d[2] = (unsigned)(qlo ? A2_ : B2_);
            yr.d[3] = (unsigned)(qlo ? A3_ : B3_);
            f32x4 e0 = __builtin_amdgcn_mfma_f32_16x16x32_bf16(w3a0.v, yr.v, b3v0, 0, 0, 0);
            f32x4 e1 = __builtin_amdgcn_mfma_f32_16x16x32_bf16(w3a1.v, yr.v, b3v1, 0, 0, 0);
            acc0 = acc0 + __builtin_elementwise_max(e0, z4);
            acc1 = acc1 + __builtin_elementwise_max(e1, z4);
#endif
        }
    }

#if HAVE_MFMA16
    float s0v = acc0[0] + acc0[1] + acc0[2] + acc0[3];
    float s1v = acc1[0] + acc1[1] + acc1[2] + acc1[3];
    s0v += __shfl_xor(s0v, 16);  s0v += __shfl_xor(s0v, 32);
    s1v += __shfl_xor(s1v, 16);  s1v += __shfl_xor(s1v, 32);
    if (l < 16) { red[w * 32 + l] = s0v;  red[w * 32 + 16 + l] = s1v; }
#else
#pragma unroll
    for (int bit = 1; bit < 16; bit <<= 1) {
#pragma unroll
        for (int r = 0; r < 4; r++) {
            acc0[r] += __shfl_xor(acc0[r], bit);
            acc1[r] += __shfl_xor(acc1[r], bit);
        }
    }
    if (p == 0) {
#pragma unroll
        for (int r = 0; r < 4; r++) {
            red[w * 32 + q * 4 + r]      = acc0[r];
            red[w * 32 + 16 + q * 4 + r] = acc1[r];
        }
    }
#endif
    __syncthreads();

    // ---- tail: GRU + u/v refresh (+ readout) ----
    if (tid < 64) {
        float val;
        if (tid < 32) val = h[j * 32 + tid];
        else {
            int s = tid - 32;
            val = red[s] + red[32 + s] + red[64 + s] + red[96 + s];
        }
        hm[tid] = val;
    }
    __syncthreads();

    if (tid < 192) {
        const int row = tid >> 1, hh = tid & 1;
        const float* wr = Wih + row * 64 + hh * 32;
        const float* hhp = hm + hh * 32;
        float acc = 0.f;
#pragma unroll
        for (int k4 = 0; k4 < 8; k4++) {
            float4 w4 = *(const float4*)(wr + 4 * k4);
            acc = fmaf(w4.x, hhp[4 * k4 + 0], acc);
            acc = fmaf(w4.y, hhp[4 * k4 + 1], acc);
            acc = fmaf(w4.z, hhp[4 * k4 + 2], acc);
            acc = fmaf(w4.w, hhp[4 * k4 + 3], acc);
        }
        acc += __shfl_xor(acc, 1);
        if (hh == 0) gbuf[row] = acc + bih[row];
    }
    __syncthreads();

    if (tid < 32) {
        const int s = tid;
        float r = sigmoidf_(gbuf[s] + bhh[s]);
        float z = sigmoidf_(gbuf[32 + s] + bhh[32 + s]);
        float n = tanhf(gbuf[64 + s] + r * bhh[64 + s]);
        float hn_ = (1.0f - z) * n;
        hnb[s] = hn_;
        h[j * 32 + s] = hn_;
    }
    __syncthreads();

    if (tid < 64) {
        const int s = tid & 31;
        const bool isV = tid >= 32;
        const float bj = b[j];
        const float* wr = W1 + s * 67 + (isV ? 32 : 0);
        float acc = isV ? fmaf(bj, W1[s * 67 + 66], b1[s]) : bj * W1[s * 67 + 65];
#pragma unroll
        for (int k = 0; k < 32; k++) acc = fmaf(wr[k], hnb[k], acc);
        if (isV) v[j * 32 + s] = acc;
        else     uo[j * 32 + s] = acc;
    }

    if (do_out) {
        __syncthreads();
        if (tid < 32) {
            float a = rb1[tid];
            const float* rr = R1 + tid * 32;
#pragma unroll 8
            for (int k = 0; k < 32; k++) a = fmaf(rr[k], hnb[k], a);
            gbuf[tid] = fmaxf(a, 0.f);
        }
        __syncthreads();
        if (tid < 32) {
            float a = rb2[tid];
            const float* rr = R2 + tid * 32;
#pragma unroll 8
            for (int k = 0; k < 32; k++) a = fmaf(rr[k], gbuf[k], a);
            tb[tid] = fmaxf(a, 0.f);
        }
        __syncthreads();
        if (tid < 2) {
            float a = rb3[tid];
            const float* rr = R3 + tid * 32;
#pragma unroll 8
            for (int k = 0; k < 32; k++) a = fmaf(rr[k], tb[k], a);
            out[j * 2 + tid] = sigmoidf_(fmaxf(a, 0.f));
        }
    }
}

// ---------------------------------------------------------------------------
extern "C" void kernel_launch(void* const* d_in, const int* in_sizes, int n_in,
                              void* d_out, int out_size, void* d_ws, size_t ws_size,
                              hipStream_t stream)
{
    const float* J   = (const float*)d_in[0];
    const float* b   = (const float*)d_in[1];
    const float* W1  = (const float*)d_in[2];
    const float* b1  = (const float*)d_in[3];
    const float* W2  = (const float*)d_in[4];
    const float* b2  = (const float*)d_in[5];
    const float* W3  = (const float*)d_in[6];
    const float* b3  = (const float*)d_in[7];
    const float* Wih = (const float*)d_in[8];
    const float* bih = (const float*)d_in[9];
    const float* bhh = (const float*)d_in[10];
    const float* R1  = (const float*)d_in[11];
    const float* rb1 = (const float*)d_in[12];
    const float* R2  = (const float*)d_in[13];
    const float* rb2 = (const float*)d_in[14];
    const float* R3  = (const float*)d_in[15];
    const float* rb3 = (const float*)d_in[16];

    float* out = (float*)d_out;
    float* ws  = (float*)d_ws;
    float* h   = ws;
    float* v   = ws + 32768;
    float* u0  = ws + 65536;
    float* u1  = ws + 98304;
    float* cfg = ws + 131072;

    k_pre<<<129, 256, 0, stream>>>(b, W1, b1, W2, b2, W3, b3, h, u0, v, cfg);
    for (int s = 0; s < 5; s++) {
        const float* ui = (s & 1) ? u1 : u0;
        float*       uo = (s & 1) ? u0 : u1;
        k_step<<<1024, 256, 0, stream>>>(J, cfg, Wih, bih, bhh, b, b1, W1,
                                         R1, rb1, R2, rb2, R3, rb3,
                                         h, v, ui, uo, out, (s == 4) ? 1 : 0);
    }
}

// Round 17
// 201.871 us; speedup vs baseline: 11.8758x; 1.1411x over previous
//
#include <hip/hip_runtime.h>
#include <math.h>

#define NN 1024

typedef __attribute__((ext_vector_type(8))) short bf16x8;
typedef __attribute__((ext_vector_type(4))) short bf16x4;
typedef __attribute__((ext_vector_type(4))) float f32x4;
typedef __attribute__((ext_vector_type(2))) float f32x2;
typedef __attribute__((ext_vector_type(4))) unsigned int u32x4;

#if __has_builtin(__builtin_amdgcn_mfma_f32_16x16x16bf16_1k)
#define HAVE_MFMA16 1
#define MFMA16(a, b, c) __builtin_amdgcn_mfma_f32_16x16x16bf16_1k((a), (b), (c), 0, 0, 0)
#else
#define HAVE_MFMA16 0
#endif

__device__ __forceinline__ float sigmoidf_(float x) { return 1.0f / (1.0f + __expf(-x)); }

__device__ __forceinline__ unsigned int pk2(float a, float b) {
    return __builtin_amdgcn_perm(__float_as_uint(a) + 0x8000u,
                                 __float_as_uint(b) + 0x8000u, 0x03020706u);
}
__device__ __forceinline__ unsigned int pkcvt(float a, float b) {
#if __has_builtin(__builtin_amdgcn_cvt_pk_bf16_f32)
    return __builtin_bit_cast(unsigned int, __builtin_amdgcn_cvt_pk_bf16_f32(a, b));
#else
    return pk2(a, b);
#endif
}
__device__ __forceinline__ unsigned short f2bf_rne(float a) {
    unsigned int ua = __float_as_uint(a);
    ua += 0x7fffu + ((ua >> 16) & 1u);
    return (unsigned short)(ua >> 16);
}
__device__ __forceinline__ unsigned int pk2b(float a, float b) {
    return (unsigned int)f2bf_rne(a) | ((unsigned int)f2bf_rne(b) << 16);
}

// cfg layout (dwords):
//  0    w2a0 | 256 w2a1 | 512 w3a0 | 768 w3a1          (A-frags, 16x16x32)
//  1024 b2v0 | 1280 b2v1 | 1536 b3v0 | 1792 b3v1       (C-layout biases)
//  2048 wj lo | 2304 wj hi
//  2560 w3T frags g-half0 | 2816 g-half1               (16x16x16 B-frags)
//  3072 b3 replicated lo | 3328 hi
#define CFG_FLOATS 3584

// ---------------------------------------------------------------------------
// k_pre: blocks 0..1023 transpose J -> Jt; 1024..1151 init h,u0,v;
//        block 1152 precomputes per-lane MFMA context into cfg.
// ---------------------------------------------------------------------------
__global__ __launch_bounds__(256) void k_pre(
    const float* __restrict__ J, const float* __restrict__ b,
    const float* __restrict__ W1, const float* __restrict__ b1,
    const float* __restrict__ W2, const float* __restrict__ b2,
    const float* __restrict__ W3, const float* __restrict__ b3,
    float* __restrict__ Jt, float* __restrict__ h,
    float* __restrict__ u0, float* __restrict__ v, float* __restrict__ cfg)
{
    __shared__ float tile[32][33];
    const int t = blockIdx.x;
    const int tid = threadIdx.x;
    if (t < 1024) {
        int tx = (t & 31) * 32, ty = (t >> 5) * 32;
        int x = tid & 31, y = tid >> 5;
#pragma unroll
        for (int r = 0; r < 4; r++)
            tile[y + 8 * r][x] = J[(size_t)(ty + y + 8 * r) * NN + tx + x];
        __syncthreads();
#pragma unroll
        for (int r = 0; r < 4; r++)
            Jt[(size_t)(tx + y + 8 * r) * NN + ty + x] = tile[x][y + 8 * r];
    } else if (t < 1152) {
        int idx = (t - 1024) * 256 + tid;
        int row = idx >> 5, mm = idx & 31;
        float bi = b[row];
        h[idx]  = 0.f;
        u0[idx] = bi * W1[mm * 67 + 65];
        v[idx]  = fmaf(bi, W1[mm * 67 + 66], b1[mm]);
    } else if (tid < 64) {
        const int l = tid, p = l & 15, q = l >> 4;
        union FU { unsigned int d[4]; unsigned short s[8]; } t0, t1, t2, t3;
        float wj[8];
#pragma unroll
        for (int jj = 0; jj < 8; jj++) {
            int k = q * 8 + jj;
            t0.s[jj] = f2bf_rne(W2[p * 32 + k]);
            t1.s[jj] = f2bf_rne(W2[(16 + p) * 32 + k]);
            t2.s[jj] = f2bf_rne(W3[p * 32 + k]);
            t3.s[jj] = f2bf_rne(W3[(16 + p) * 32 + k]);
            wj[jj] = W1[k * 67 + 64];
        }
        u32x4* cw = (u32x4*)cfg;
        cw[l]       = *(u32x4*)t0.d;
        cw[64 + l]  = *(u32x4*)t1.d;
        cw[128 + l] = *(u32x4*)t2.d;
        cw[192 + l] = *(u32x4*)t3.d;
        f32x4* cf = (f32x4*)(cfg + 1024);
        f32x4 v0, v1, v2, v3;
#pragma unroll
        for (int r = 0; r < 4; r++) {
            v0[r] = b2[q * 4 + r];  v1[r] = b2[16 + q * 4 + r];
            v2[r] = b3[q * 4 + r];  v3[r] = b3[16 + q * 4 + r];
        }
        cf[l] = v0; cf[64 + l] = v1; cf[128 + l] = v2; cf[192 + l] = v3;
        f32x4* cj = (f32x4*)(cfg + 2048);
        f32x4 wlo, whi;
#pragma unroll
        for (int r = 0; r < 4; r++) { wlo[r] = wj[r]; whi[r] = wj[4 + r]; }
        cj[l] = wlo; cj[64 + l] = whi;

        const int g = p;
        u32x4 fa, fb;
        fa[0] = pk2b(W3[g * 32 + 4 * q + 0],      W3[g * 32 + 4 * q + 1]);
        fa[1] = pk2b(W3[g * 32 + 4 * q + 2],      W3[g * 32 + 4 * q + 3]);
        fa[2] = pk2b(W3[g * 32 + 16 + 4 * q + 0], W3[g * 32 + 16 + 4 * q + 1]);
        fa[3] = pk2b(W3[g * 32 + 16 + 4 * q + 2], W3[g * 32 + 16 + 4 * q + 3]);
        fb[0] = pk2b(W3[(16 + g) * 32 + 4 * q + 0],      W3[(16 + g) * 32 + 4 * q + 1]);
        fb[1] = pk2b(W3[(16 + g) * 32 + 4 * q + 2],      W3[(16 + g) * 32 + 4 * q + 3]);
        fb[2] = pk2b(W3[(16 + g) * 32 + 16 + 4 * q + 0], W3[(16 + g) * 32 + 16 + 4 * q + 1]);
        fb[3] = pk2b(W3[(16 + g) * 32 + 16 + 4 * q + 2], W3[(16 + g) * 32 + 16 + 4 * q + 3]);
        u32x4* cw2 = (u32x4*)(cfg + 2560);
        cw2[l] = fa; cw2[64 + l] = fb;
        f32x4* cb3 = (f32x4*)(cfg + 3072);
        f32x4 r0, r1;
#pragma unroll
        for (int r = 0; r < 4; r++) { r0[r] = b3[g]; r1[r] = b3[16 + g]; }
        cb3[l] = r0; cb3[64 + l] = r1;
    }
}

// ---------------------------------------------------------------------------
// k_step: one recurrence step, tail fused. 1024 blocks x 256 threads,
// 4 waves x 16 tiles (8 pairs), depth-2 pair prefetch.
// GEMM3 consumes GEMM2's C-layout directly via 4 chained 16x16x16 MFMAs
// (register dataflow, no LDS-pipe relayout).  Fallback: bpermute path.
// ---------------------------------------------------------------------------
__global__ __launch_bounds__(256, 4) void k_step(
    const float* __restrict__ Jt, const float* __restrict__ cfg,
    const float* __restrict__ Wih, const float* __restrict__ bih,
    const float* __restrict__ bhh, const float* __restrict__ b,
    const float* __restrict__ b1, const float* __restrict__ W1,
    const float* __restrict__ R1, const float* __restrict__ rb1,
    const float* __restrict__ R2, const float* __restrict__ rb2,
    const float* __restrict__ R3, const float* __restrict__ rb3,
    float* __restrict__ h, float* __restrict__ v,
    const float* __restrict__ ui, float* __restrict__ uo,
    float* __restrict__ out, int do_out)
{
    __shared__ float red[4 * 32];
    __shared__ float hm[64], gbuf[96], hnb[32], tb[32];

    const int tid = threadIdx.x;
    const int w = tid >> 6;
    const int l = tid & 63;
    const int p = l & 15;
    const int q = l >> 4;
    const int j = blockIdx.x;

    // ---- coalesced per-lane context ----
    union FU { bf16x8 v; u32x4 u4; } w2a0, w2a1;
    const u32x4* cw = (const u32x4*)cfg;
    w2a0.u4 = cw[l]; w2a1.u4 = cw[64 + l];
    const f32x4* cf = (const f32x4*)(cfg + 1024);
    const f32x4 b2v0 = cf[l], b2v1 = cf[64 + l];
    const f32x4* cj = (const f32x4*)(cfg + 2048);
    const f32x4 wlo = cj[l], whi = cj[64 + l];
    f32x2 wj2[4] = { {wlo[0], wlo[1]}, {wlo[2], wlo[3]}, {whi[0], whi[1]}, {whi[2], whi[3]} };

#if HAVE_MFMA16
    union B4 { bf16x4 v; unsigned int d[2]; } B0a, B1a, B0b, B1b;
    {
        const u32x4* cw2 = (const u32x4*)(cfg + 2560);
        u32x4 fa = cw2[l], fb = cw2[64 + l];
        B0a.d[0] = fa[0]; B0a.d[1] = fa[1]; B1a.d[0] = fa[2]; B1a.d[1] = fa[3];
        B0b.d[0] = fb[0]; B0b.d[1] = fb[1]; B1b.d[0] = fb[2]; B1b.d[1] = fb[3];
    }
    const f32x4* cb3 = (const f32x4*)(cfg + 3072);
    const f32x4 b3lo = cb3[l], b3hi = cb3[64 + l];
#else
    union FU w3a0, w3a1;
    w3a0.u4 = cw[128 + l]; w3a1.u4 = cw[192 + l];
    const f32x4 b3v0 = cf[128 + l], b3v1 = cf[192 + l];
    const int s0 = (p | ((l & 16) << 1)) << 2;
    const int s1 = s0 + 64;
    const bool qlo = (l & 32) == 0;
#endif

    f32x2 vv2[4];
    {
        float4 va = *(const float4*)(v + j * 32 + q * 8);
        float4 vb = *(const float4*)(v + j * 32 + q * 8 + 4);
        vv2[0] = f32x2{va.x, va.y}; vv2[1] = f32x2{va.z, va.w};
        vv2[2] = f32x2{vb.x, vb.y}; vv2[3] = f32x2{vb.z, vb.w};
    }

    f32x4 acc0 = {0.f, 0.f, 0.f, 0.f}, acc1 = {0.f, 0.f, 0.f, 0.f};

    // ---- depth-2 pair prefetch (4 tiles in flight) ----
    const int ibase = w * 256;
    const float* jp = Jt + (size_t)j * NN + ibase + p;
    const float* up = ui + (size_t)(ibase + p) * 32 + q * 8;

    float  jw0[2], jw1[2];
    float4 ua0[2], ub0[2], ua1[2], ub1[2];
#pragma unroll
    for (int s = 0; s < 2; s++) {
        jw0[s] = jp[s * 32];       jw1[s] = jp[s * 32 + 16];
        ua0[s] = *(const float4*)(up + (size_t)s * 1024);
        ub0[s] = *(const float4*)(up + (size_t)s * 1024 + 4);
        ua1[s] = *(const float4*)(up + (size_t)s * 1024 + 512);
        ub1[s] = *(const float4*)(up + (size_t)s * 1024 + 516);
    }

#pragma unroll
    for (int tt = 0; tt < 8; ++tt) {
        const int sl = tt & 1;
        const float  jwA_c = jw0[sl], jwB_c = jw1[sl];
        const float4 uaA_c = ua0[sl], ubA_c = ub0[sl];
        const float4 uaB_c = ua1[sl], ubB_c = ub1[sl];
        if (tt < 6) {
            const float* jn = jp + (tt + 2) * 32;
            const float* un = up + (size_t)(tt + 2) * 1024;
            jw0[sl] = jn[0];  jw1[sl] = jn[16];
            ua0[sl] = *(const float4*)(un);
            ub0[sl] = *(const float4*)(un + 4);
            ua1[sl] = *(const float4*)(un + 512);
            ub1[sl] = *(const float4*)(un + 516);
        }

#pragma unroll
        for (int half = 0; half < 2; ++half) {
            const float  jw = half ? jwB_c : jwA_c;
            const float4 ua_c = half ? uaB_c : uaA_c;
            const float4 ub_c = half ? ubB_c : ubA_c;

            const f32x2 jw2 = {jw, jw};
            const f32x2 z2 = {0.f, 0.f};
            const f32x4 z4 = {0.f, 0.f, 0.f, 0.f};

            f32x2 x0 = {ua_c.x, ua_c.y}, x1 = {ua_c.z, ua_c.w};
            f32x2 x2 = {ub_c.x, ub_c.y}, x3 = {ub_c.z, ub_c.w};
            x0 = jw2 * wj2[0] + (x0 + vv2[0]);
            x1 = jw2 * wj2[1] + (x1 + vv2[1]);
            x2 = jw2 * wj2[2] + (x2 + vv2[2]);
            x3 = jw2 * wj2[3] + (x3 + vv2[3]);
            x0 = __builtin_elementwise_max(x0, z2);
            x1 = __builtin_elementwise_max(x1, z2);
            x2 = __builtin_elementwise_max(x2, z2);
            x3 = __builtin_elementwise_max(x3, z2);

            union BU { u32x4 u4; bf16x8 v; unsigned int d[4]; } bx;
            bx.d[0] = pkcvt(x0[0], x0[1]);
            bx.d[1] = pkcvt(x1[0], x1[1]);
            bx.d[2] = pkcvt(x2[0], x2[1]);
            bx.d[3] = pkcvt(x3[0], x3[1]);

            f32x4 c0 = __builtin_amdgcn_mfma_f32_16x16x32_bf16(w2a0.v, bx.v, b2v0, 0, 0, 0);
            f32x4 c1 = __builtin_amdgcn_mfma_f32_16x16x32_bf16(w2a1.v, bx.v, b2v1, 0, 0, 0);
            c0 = __builtin_elementwise_max(c0, z4);
            c1 = __builtin_elementwise_max(c1, z4);

#if HAVE_MFMA16
            // Z (= Y^T) is already in A-operand layout of 16x16x16.
            union B4 { bf16x4 v; unsigned int d[2]; } A0, A1;
            A0.d[0] = pkcvt(c0[0], c0[1]); A0.d[1] = pkcvt(c0[2], c0[3]);
            A1.d[0] = pkcvt(c1[0], c1[1]); A1.d[1] = pkcvt(c1[2], c1[3]);

            f32x4 e0 = MFMA16(A0.v, B0a.v, b3lo);
            e0 = MFMA16(A1.v, B1a.v, e0);
            f32x4 e1 = MFMA16(A0.v, B0b.v, b3hi);
            e1 = MFMA16(A1.v, B1b.v, e1);
            acc0 = acc0 + __builtin_elementwise_max(e0, z4);
            acc1 = acc1 + __builtin_elementwise_max(e1, z4);
#else
            const int d0 = (int)pkcvt(c0[0], c0[1]);
            const int d1 = (int)pkcvt(c0[2], c0[3]);
            const int d2 = (int)pkcvt(c1[0], c1[1]);
            const int d3 = (int)pkcvt(c1[2], c1[3]);
            const int A0_ = __builtin_amdgcn_ds_bpermute(s0, d0);
            const int A1_ = __builtin_amdgcn_ds_bpermute(s0, d1);
            const int A2_ = __builtin_amdgcn_ds_bpermute(s1, d0);
            const int A3_ = __builtin_amdgcn_ds_bpermute(s1, d1);
            const int B0_ = __builtin_amdgcn_ds_bpermute(s0, d2);
            const int B1_ = __builtin_amdgcn_ds_bpermute(s0, d3);
            const int B2_ = __builtin_amdgcn_ds_bpermute(s1, d2);
            const int B3_ = __builtin_amdgcn_ds_bpermute(s1, d3);
            union BU yr;
            yr.d[0] = (unsigned)(qlo ? A0_ : B0_);
            yr.d[1] = (unsigned)(qlo ? A1_ : B1_);
            yr.d[2] = (unsigned)(qlo ? A2_ : B2_);
            yr.d[3] = (unsigned)(qlo ? A3_ : B3_);
            f32x4 e0 = __builtin_amdgcn_mfma_f32_16x16x32_bf16(w3a0.v, yr.v, b3v0, 0, 0, 0);
            f32x4 e1 = __builtin_amdgcn_mfma_f32_16x16x32_bf16(w3a1.v, yr.v, b3v1, 0, 0, 0);
            acc0 = acc0 + __builtin_elementwise_max(e0, z4);
            acc1 = acc1 + __builtin_elementwise_max(e1, z4);
#endif
        }
    }

#if HAVE_MFMA16
    // acc lane layout: col g = l&15 (acc0: g, acc1: 16+g), rows p = 4q+r.
    float s0v = acc0[0] + acc0[1] + acc0[2] + acc0[3];
    float s1v = acc1[0] + acc1[1] + acc1[2] + acc1[3];
    s0v += __shfl_xor(s0v, 16);  s0v += __shfl_xor(s0v, 32);
    s1v += __shfl_xor(s1v, 16);  s1v += __shfl_xor(s1v, 32);
    if (l < 16) { red[w * 32 + l] = s0v;  red[w * 32 + 16 + l] = s1v; }
#else
#pragma unroll
    for (int bit = 1; bit < 16; bit <<= 1) {
#pragma unroll
        for (int r = 0; r < 4; r++) {
            acc0[r] += __shfl_xor(acc0[r], bit);
            acc1[r] += __shfl_xor(acc1[r], bit);
        }
    }
    if (p == 0) {
#pragma unroll
        for (int r = 0; r < 4; r++) {
            red[w * 32 + q * 4 + r]      = acc0[r];
            red[w * 32 + 16 + q * 4 + r] = acc1[r];
        }
    }
#endif
    __syncthreads();

    // ---- tail: GRU + u/v refresh (+ readout) ----
    if (tid < 64) {
        float val;
        if (tid < 32) val = h[j * 32 + tid];
        else {
            int s = tid - 32;
            val = red[s] + red[32 + s] + red[64 + s] + red[96 + s];
        }
        hm[tid] = val;
    }
    __syncthreads();

    if (tid < 192) {
        const int row = tid >> 1, half = tid & 1;
        const float* wr = Wih + row * 64 + half * 32;
        const float* hh = hm + half * 32;
        float acc = 0.f;
#pragma unroll
        for (int k4 = 0; k4 < 8; k4++) {
            float4 w4 = *(const float4*)(wr + 4 * k4);
            acc = fmaf(w4.x, hh[4 * k4 + 0], acc);
            acc = fmaf(w4.y, hh[4 * k4 + 1], acc);
            acc = fmaf(w4.z, hh[4 * k4 + 2], acc);
            acc = fmaf(w4.w, hh[4 * k4 + 3], acc);
        }
        acc += __shfl_xor(acc, 1);
        if (half == 0) gbuf[row] = acc + bih[row];
    }
    __syncthreads();

    if (tid < 32) {
        const int s = tid;
        float r = sigmoidf_(gbuf[s] + bhh[s]);
        float z = sigmoidf_(gbuf[32 + s] + bhh[32 + s]);
        float n = tanhf(gbuf[64 + s] + r * bhh[64 + s]);
        float hn_ = (1.0f - z) * n;
        hnb[s] = hn_;
        h[j * 32 + s] = hn_;
    }
    __syncthreads();

    if (tid < 64) {
        const int s = tid & 31;
        const bool isV = tid >= 32;
        const float bj = b[j];
        const float* wr = W1 + s * 67 + (isV ? 32 : 0);
        float acc = isV ? fmaf(bj, W1[s * 67 + 66], b1[s]) : bj * W1[s * 67 + 65];
#pragma unroll
        for (int k = 0; k < 32; k++) acc = fmaf(wr[k], hnb[k], acc);
        if (isV) v[j * 32 + s] = acc;
        else     uo[j * 32 + s] = acc;
    }

    if (do_out) {
        __syncthreads();
        if (tid < 32) {
            float a = rb1[tid];
            const float* rr = R1 + tid * 32;
#pragma unroll 8
            for (int k = 0; k < 32; k++) a = fmaf(rr[k], hnb[k], a);
            gbuf[tid] = fmaxf(a, 0.f);
        }
        __syncthreads();
        if (tid < 32) {
            float a = rb2[tid];
            const float* rr = R2 + tid * 32;
#pragma unroll 8
            for (int k = 0; k < 32; k++) a = fmaf(rr[k], gbuf[k], a);
            tb[tid] = fmaxf(a, 0.f);
        }
        __syncthreads();
        if (tid < 2) {
            float a = rb3[tid];
            const float* rr = R3 + tid * 32;
#pragma unroll 8
            for (int k = 0; k < 32; k++) a = fmaf(rr[k], tb[k], a);
            out[j * 2 + tid] = sigmoidf_(fmaxf(a, 0.f));
        }
    }
}

// ---------------------------------------------------------------------------
extern "C" void kernel_launch(void* const* d_in, const int* in_sizes, int n_in,
                              void* d_out, int out_size, void* d_ws, size_t ws_size,
                              hipStream_t stream)
{
    const float* J   = (const float*)d_in[0];
    const float* b   = (const float*)d_in[1];
    const float* W1  = (const float*)d_in[2];
    const float* b1  = (const float*)d_in[3];
    const float* W2  = (const float*)d_in[4];
    const float* b2  = (const float*)d_in[5];
    const float* W3  = (const float*)d_in[6];
    const float* b3  = (const float*)d_in[7];
    const float* Wih = (const float*)d_in[8];
    const float* bih = (const float*)d_in[9];
    const float* bhh = (const float*)d_in[10];
    const float* R1  = (const float*)d_in[11];
    const float* rb1 = (const float*)d_in[12];
    const float* R2  = (const float*)d_in[13];
    const float* rb2 = (const float*)d_in[14];
    const float* R3  = (const float*)d_in[15];
    const float* rb3 = (const float*)d_in[16];

    float* out = (float*)d_out;
    float* ws  = (float*)d_ws;
    float* h   = ws;
    float* v   = ws + 32768;
    float* u0  = ws + 65536;
    float* u1  = ws + 98304;
    float* Jt  = ws + 131072;
    float* cfg = ws + 131072 + NN * NN;

    k_pre<<<1153, 256, 0, stream>>>(J, b, W1, b1, W2, b2, W3, b3,
                                    Jt, h, u0, v, cfg);
    for (int s = 0; s < 5; s++) {
        const float* ui = (s & 1) ? u1 : u0;
        float*       uo = (s & 1) ? u0 : u1;
        k_step<<<1024, 256, 0, stream>>>(Jt, cfg, Wih, bih, bhh, b, b1, W1,
                                         R1, rb1, R2, rb2, R3, rb3,
                                         h, v, ui, uo, out, (s == 4) ? 1 : 0);
    }
}